// Round 3
// baseline (270.494 us; speedup 1.0000x reference)
//
#include <hip/hip_runtime.h>

typedef unsigned short ushort_t;
typedef __attribute__((ext_vector_type(8)))  short  short8;
typedef __attribute__((ext_vector_type(4)))  short  short4v;
typedef __attribute__((ext_vector_type(4)))  float  float4v;
typedef __attribute__((ext_vector_type(4)))  int    int4v;

#define N_NODES 4096
#define NHEADS  4
#define DK      128
#define ODIM    512
#define KDIM    512

__device__ __forceinline__ float bf2f(ushort_t u) {
    return __uint_as_float(((unsigned)u) << 16);
}
__device__ __forceinline__ ushort_t f2bf_rne(float f) {
    unsigned u = __float_as_uint(f);
    u += 0x7fffu + ((u >> 16) & 1u);
    return (ushort_t)(u >> 16);
}

// ---------------------------------------------------------------------------
// Kernel 1: bit-pack mask = (A != 0) || (i == j); block 0 wave 0 also runs the
// input-dtype detector (1 = fp32 inputs).  int4 loads + 16-lane shfl-OR pack.
// ---------------------------------------------------------------------------
__global__ __launch_bounds__(256) void pack_mask_k(const int* __restrict__ A,
                                                   unsigned long long* __restrict__ P,
                                                   const ushort_t* __restrict__ Hraw,
                                                   int* __restrict__ flag)
{
    if (blockIdx.x == 0 && threadIdx.x < 64) {
        const int lane = threadIdx.x;
        int cnt = 0;
        #pragma unroll
        for (int s = 0; s < 16; ++s) {
            ushort_t v = Hraw[(lane * 16 + s) * 2];
            int e = (v >> 7) & 0xFF;
            cnt += (((e >= 90) && (e <= 140)) || (v == 0)) ? 1 : 0;
        }
        #pragma unroll
        for (int off = 32; off; off >>= 1) cnt += __shfl_down(cnt, off);
        if (lane == 0) *flag = (cnt < 768) ? 1 : 0;
    }
    const int tid  = threadIdx.x;
    const int lane = tid & 63;
    const int flat4 = blockIdx.x * 256 + tid;     // index in units of int4
    const int row   = flat4 >> 10;                // (flat4*4) >> 12
    const int col0  = (flat4 << 2) & 4095;
    const int4v a   = ((const int4v*)A)[flat4];
    unsigned nib = 0;
    #pragma unroll
    for (int j = 0; j < 4; ++j)
        nib |= ((a[j] != 0) || (row == col0 + j)) ? (1u << j) : 0u;
    unsigned long long v = (unsigned long long)nib << ((lane & 15) * 4);
    v |= __shfl_xor(v, 1);
    v |= __shfl_xor(v, 2);
    v |= __shfl_xor(v, 4);
    v |= __shfl_xor(v, 8);
    if ((lane & 15) == 0) P[flat4 >> 4] = v;
}

// ---------------------------------------------------------------------------
// Kernel 2: WT[n][k] = W[k][n] as bf16 (dual-dtype input).
// ---------------------------------------------------------------------------
__global__ __launch_bounds__(256) void transpose_w_k(const void* __restrict__ W,
                                                     ushort_t* __restrict__ WT,
                                                     const int* __restrict__ flag)
{
    __shared__ ushort_t lt[64][72];
    const int f32 = *flag;
    const int tid = threadIdx.x;
    const int ti = blockIdx.x >> 3, tj = blockIdx.x & 7;
    const int r = tid >> 2, c2 = tid & 3;
    const size_t eo = (size_t)(ti * 64 + r) * KDIM + tj * 64 + c2 * 16;
    if (f32) {
        const float4v* src = (const float4v*)((const float*)W + eo);
        float4v f0 = src[0], f1 = src[1], f2 = src[2], f3 = src[3];
        #pragma unroll
        for (int e = 0; e < 4; ++e) {
            lt[r][c2 * 16 +  0 + e] = f2bf_rne(f0[e]);
            lt[r][c2 * 16 +  4 + e] = f2bf_rne(f1[e]);
            lt[r][c2 * 16 +  8 + e] = f2bf_rne(f2[e]);
            lt[r][c2 * 16 + 12 + e] = f2bf_rne(f3[e]);
        }
    } else {
        const short8* src = (const short8*)((const ushort_t*)W + eo);
        short8 v0 = src[0];
        short8 v1 = src[1];
        *(short8*)&lt[r][c2 * 16]     = v0;
        *(short8*)&lt[r][c2 * 16 + 8] = v1;
    }
    __syncthreads();
    #pragma unroll
    for (int itr = 0; itr < 2; ++itr) {
        int idx = itr * 256 + tid;
        int n = idx >> 3, c = idx & 7;
        short8 vv;
        #pragma unroll
        for (int e = 0; e < 8; ++e) vv[e] = (short)lt[c * 8 + e][n];
        *(short8*)(WT + (size_t)(tj * 64 + n) * KDIM + ti * 64 + c * 8) = vv;
    }
}

// ---------------------------------------------------------------------------
// Kernel 3: WhT[n][i] = (H @ W)[i][n].  16x16x32 MFMA, dual-dtype A loads.
// v13: bm = bx&63 (was bx>>3) so all 8 bn-blocks of one H-panel land on the
// same XCD (XCD = bx%8 = f(bm)) -> H fetched once from HBM (~-56 MB).
// ---------------------------------------------------------------------------
__global__ __launch_bounds__(256) void gemm_wht_dual_k(const void* __restrict__ H,
                                                       const ushort_t* __restrict__ WT,
                                                       ushort_t* __restrict__ WhT,
                                                       const int* __restrict__ flag)
{
    __shared__ ushort_t lt[64][72];
    const int f32 = *flag;
    const int tid  = threadIdx.x;
    const int lane = tid & 63;
    const int wid  = tid >> 6;
    const int quad = lane >> 4;
    const int l15  = lane & 15;
    const int bm = blockIdx.x & 63, bn = blockIdx.x >> 6;
    const int i0 = bm * 64, n0 = bn * 64;

    const size_t aoff = (size_t)(i0 + wid * 16 + l15) * KDIM + quad * 8;
    const short8* bp0 = (const short8*)(WT + (size_t)(n0 +  0 + l15) * KDIM) + quad;
    const short8* bp1 = (const short8*)(WT + (size_t)(n0 + 16 + l15) * KDIM) + quad;
    const short8* bp2 = (const short8*)(WT + (size_t)(n0 + 32 + l15) * KDIM) + quad;
    const short8* bp3 = (const short8*)(WT + (size_t)(n0 + 48 + l15) * KDIM) + quad;

    float4v acc0, acc1, acc2, acc3;
    #pragma unroll
    for (int e = 0; e < 4; ++e) { acc0[e] = 0.f; acc1[e] = 0.f; acc2[e] = 0.f; acc3[e] = 0.f; }

    #pragma unroll 4
    for (int k8 = 0; k8 < 64; k8 += 4) {
        short8 a;
        if (f32) {
            const float4v* fp = (const float4v*)((const float*)H + aoff + (size_t)k8 * 8);
            float4v x0 = fp[0], x1 = fp[1];
            #pragma unroll
            for (int e = 0; e < 4; ++e) {
                a[e]     = (short)f2bf_rne(x0[e]);
                a[4 + e] = (short)f2bf_rne(x1[e]);
            }
        } else {
            a = *(const short8*)((const ushort_t*)H + aoff + (size_t)k8 * 8);
        }
        acc0 = __builtin_amdgcn_mfma_f32_16x16x32_bf16(a, bp0[k8], acc0, 0, 0, 0);
        acc1 = __builtin_amdgcn_mfma_f32_16x16x32_bf16(a, bp1[k8], acc1, 0, 0, 0);
        acc2 = __builtin_amdgcn_mfma_f32_16x16x32_bf16(a, bp2[k8], acc2, 0, 0, 0);
        acc3 = __builtin_amdgcn_mfma_f32_16x16x32_bf16(a, bp3[k8], acc3, 0, 0, 0);
    }

    #pragma unroll
    for (int r = 0; r < 4; ++r) {
        int m = wid * 16 + quad * 4 + r;
        lt[ 0 + l15][m] = f2bf_rne(acc0[r]);
        lt[16 + l15][m] = f2bf_rne(acc1[r]);
        lt[32 + l15][m] = f2bf_rne(acc2[r]);
        lt[48 + l15][m] = f2bf_rne(acc3[r]);
    }
    __syncthreads();
    #pragma unroll
    for (int itr = 0; itr < 2; ++itr) {
        int idx = itr * 256 + tid;
        int n = idx >> 3, c = idx & 7;
        short8 v = *(const short8*)&lt[n][c * 8];
        *(short8*)(WhT + (size_t)(n0 + n) * N_NODES + i0 + c * 8) = v;
    }
}

// ---------------------------------------------------------------------------
// Kernel 4: sl[h][i], sr[h][i] from WhT (bf16) and a_l/a_r (dual-dtype).
// ---------------------------------------------------------------------------
__global__ __launch_bounds__(256) void slsr_k(const ushort_t* __restrict__ WhT,
                                              const void* __restrict__ al,
                                              const void* __restrict__ ar,
                                              float* __restrict__ sl,
                                              float* __restrict__ sr,
                                              const int* __restrict__ flag)
{
    const int f32 = *flag;
    const int b = blockIdx.x;
    const int h = b >> 4;
    const int i = ((b & 15) << 8) + threadIdx.x;
    float asl = 0.f, asr = 0.f;
    #pragma unroll 8
    for (int d = 0; d < DK; ++d) {
        float v  = bf2f(WhT[(size_t)(h * DK + d) * N_NODES + i]);
        float av = f32 ? ((const float*)al)[h * DK + d] : bf2f(((const ushort_t*)al)[h * DK + d]);
        float bv = f32 ? ((const float*)ar)[h * DK + d] : bf2f(((const ushort_t*)ar)[h * DK + d]);
        asl += v * av;
        asr += v * bv;
    }
    sl[h * N_NODES + i] = asl;
    sr[h * N_NODES + i] = asr;
}

// ---------------------------------------------------------------------------
// Kernel 5 v13: register-double-buffered V (T14 issue-early/consume-late).
// v12 diagnosis: all pipes <40% busy, >70% SIMD-idle at 2 waves/SIMD (80KB
// LDS -> 2 blocks/CU).  The 64KB vbuf existed only as a prefetch engine; a
// reg dbuf gives the same counted-vmcnt prefetch (compiler emits precise
// per-register vmcnt(8) waits for register loads — unlike global_load_lds)
// while freeing 64KB LDS and the 8 ds_read_b128/iter.  VGPR ~165 ->
// __launch_bounds__(256,3) = 3 waves/SIMD (+50% latency hiding).  v11
// proved the direct-global fragment addressing numerically correct; its
// failure was the missing prefetch structure, restored here.
// Per iter: [pf(VALU, srs/mbuf LDS)] [issue 8 loads -> bf_nxt]
//           [MFMA(pf, bf_cur) under setprio(1)] ; roles alternate even/odd.
// ---------------------------------------------------------------------------
__global__ __launch_bounds__(256, 3) void attn_split_k(const ushort_t* __restrict__ WhT,
                                                       const unsigned* __restrict__ Apack,
                                                       const float* __restrict__ sl,
                                                       const float* __restrict__ sr,
                                                       float* __restrict__ Npart,
                                                       float* __restrict__ Dpart)
{
    __shared__ float    srs[2048];          // 8 KB, sr*C1 for this half
    __shared__ unsigned mbuf[32][64];       // 8 KB, XOR-swizzled cols
    __shared__ float    red[32 * 128];      // 16 KB epilogue reduction
    __shared__ float    lsum[128];          // 0.5 KB

    const int tid  = threadIdx.x;
    const int lane = tid & 63;
    const int wq   = tid >> 6;               // j-quarter of the half
    const int quad = lane >> 4;
    const int l15  = lane & 15;
    const int bx   = blockIdx.x;
    const int half = bx & 1;
    const int h    = (bx >> 1) & 3;
    const int i0   = (bx >> 3) << 5;         // 32-row tile
    const int jbase = half << 11;            // 0 or 2048

    const float C1 = 1.44269504f;             // log2(e)

    for (int j = tid; j < 2048; j += 256) srs[j] = sr[h * N_NODES + jbase + j] * C1;
    for (int t = tid; t < 32 * 64; t += 256) {
        int r = t >> 6, c = t & 63;
        mbuf[r][c ^ r] = Apack[(size_t)(i0 + r) * 128 + (half << 6) + c];
    }
    const float slv0 = sl[h * N_NODES + i0 + l15] * C1;
    const float slv1 = sl[h * N_NODES + i0 + 16 + l15] * C1;
    __syncthreads();                          // staging done; no loop barriers

    float4v acc[2][8];
    #pragma unroll
    for (int mg = 0; mg < 2; ++mg)
        #pragma unroll
        for (int nt = 0; nt < 8; ++nt)
            #pragma unroll
            for (int e = 0; e < 4; ++e) acc[mg][nt][e] = 0.f;
    float4v accden0, accden1;
    #pragma unroll
    for (int e = 0; e < 4; ++e) { accden0[e] = 0.f; accden1[e] = 0.f; }

    short8 ones;
    #pragma unroll
    for (int e = 0; e < 8; ++e) ones[e] = (short)0x3F80;   // bf16 1.0

    // B-fragment base: row = h*DK + l15 (+ nt*16), k = jl + quad*8
    const ushort_t* vb = WhT + (size_t)(h * DK + l15) * N_NODES + jbase + wq * 512 + quad * 8;

    short8 bfA[8], bfB[8];

    // prologue: load window 0 into bfA
    #pragma unroll
    for (int nt = 0; nt < 8; ++nt)
        bfA[nt] = *(const short8*)(vb + (size_t)nt * 16 * N_NODES);

    #define PF_COMPUTE(IT, PF0, PF1)                                               \
        {   const int jl_ = wq * 512 + (IT) * 32;                                  \
            const int mc_ = jl_ >> 5;                                              \
            const unsigned wa_ = mbuf[l15][mc_ ^ l15];                             \
            const unsigned wb_ = mbuf[16 + l15][mc_ ^ (16 + l15)];                 \
            const float4v s0_ = *(const float4v*)&srs[jl_ + quad * 8];             \
            const float4v s1_ = *(const float4v*)&srs[jl_ + quad * 8 + 4];         \
            _Pragma("unroll")                                                      \
            for (int jj = 0; jj < 8; ++jj) {                                       \
                float srj = (jj < 4) ? s0_[jj] : s1_[jj - 4];                      \
                int bit = quad * 8 + jj;                                           \
                float x0 = slv0 + srj;                                             \
                float t0 = fmaxf(x0, x0 * 0.2f);                                   \
                t0 = ((wa_ >> bit) & 1u) ? t0 : -1e30f;                            \
                PF0[jj] = (short)(ushort_t)(__float_as_uint(__builtin_amdgcn_exp2f(t0)) >> 16); \
                float x1 = slv1 + srj;                                             \
                float t1 = fmaxf(x1, x1 * 0.2f);                                   \
                t1 = ((wb_ >> bit) & 1u) ? t1 : -1e30f;                            \
                PF1[jj] = (short)(ushort_t)(__float_as_uint(__builtin_amdgcn_exp2f(t1)) >> 16); \
            } }

    #define LOAD_WIN(IT, DST)                                                      \
        { _Pragma("unroll")                                                        \
          for (int nt = 0; nt < 8; ++nt)                                           \
            DST[nt] = *(const short8*)(vb + (size_t)nt * 16 * N_NODES + (IT) * 32); }

    #define MFMA_WIN(BF, PF0, PF1)                                                 \
        {   __builtin_amdgcn_s_setprio(1);                                         \
            _Pragma("unroll")                                                      \
            for (int nt = 0; nt < 8; ++nt) {                                       \
                acc[0][nt] = __builtin_amdgcn_mfma_f32_16x16x32_bf16(PF0, BF[nt], acc[0][nt], 0, 0, 0); \
                acc[1][nt] = __builtin_amdgcn_mfma_f32_16x16x32_bf16(PF1, BF[nt], acc[1][nt], 0, 0, 0); \
            }                                                                      \
            accden0 = __builtin_amdgcn_mfma_f32_16x16x32_bf16(PF0, ones, accden0, 0, 0, 0); \
            accden1 = __builtin_amdgcn_mfma_f32_16x16x32_bf16(PF1, ones, accden1, 0, 0, 0); \
            __builtin_amdgcn_s_setprio(0); }

    #pragma unroll 1
    for (int it2 = 0; it2 < 8; ++it2) {
        const int itE = it2 * 2;
        // even phase: consume bfA, prefetch bfB
        short8 pf0, pf1;
        PF_COMPUTE(itE, pf0, pf1)
        LOAD_WIN(itE + 1, bfB)
        MFMA_WIN(bfA, pf0, pf1)
        // odd phase: consume bfB, prefetch bfA
        short8 pf2, pf3;
        PF_COMPUTE(itE + 1, pf2, pf3)
        if (it2 < 7) LOAD_WIN(itE + 2, bfA)
        MFMA_WIN(bfB, pf2, pf3)
    }
    #undef PF_COMPUTE
    #undef LOAD_WIN
    #undef MFMA_WIN

    // ---- epilogue: cross-wave reduction over j-quarters ----
    __syncthreads();

    if (l15 == 0) {
        #pragma unroll
        for (int r = 0; r < 4; ++r) {
            lsum[wq * 32 + quad * 4 + r]      = accden0[r];
            lsum[wq * 32 + 16 + quad * 4 + r] = accden1[r];
        }
    }
    #define RED_WRITE                                                                \
        { _Pragma("unroll")                                                          \
          for (int mg = 0; mg < 2; ++mg)                                             \
            _Pragma("unroll")                                                        \
            for (int nt = 0; nt < 8; ++nt)                                           \
              _Pragma("unroll")                                                      \
              for (int r = 0; r < 4; ++r)                                            \
                red[(mg * 16 + quad * 4 + r) * 128 + nt * 16 + l15] = acc[mg][nt][r]; }
    #define RED_ADD                                                                 \
        { _Pragma("unroll")                                                          \
          for (int mg = 0; mg < 2; ++mg)                                             \
            _Pragma("unroll")                                                        \
            for (int nt = 0; nt < 8; ++nt)                                           \
              _Pragma("unroll")                                                      \
              for (int r = 0; r < 4; ++r)                                            \
                acc[mg][nt][r] += red[(mg * 16 + quad * 4 + r) * 128 + nt * 16 + l15]; }

    if (wq == 1) RED_WRITE
    __syncthreads();
    if (wq == 0) RED_ADD
    __syncthreads();
    if (wq == 3) RED_WRITE
    __syncthreads();
    if (wq == 2) RED_ADD
    __syncthreads();
    if (wq == 2) RED_WRITE
    __syncthreads();
    if (wq == 0) {
        RED_ADD
        float* Np = Npart + (size_t)half * N_NODES * ODIM;
        #pragma unroll
        for (int mg = 0; mg < 2; ++mg)
            #pragma unroll
            for (int nt = 0; nt < 8; ++nt)
                #pragma unroll
                for (int r = 0; r < 4; ++r) {
                    int rowi = mg * 16 + quad * 4 + r;
                    Np[(size_t)(i0 + rowi) * ODIM + h * DK + nt * 16 + l15] = acc[mg][nt][r];
                }
        if (l15 == 0) {
            #pragma unroll
            for (int mg = 0; mg < 2; ++mg)
                #pragma unroll
                for (int r = 0; r < 4; ++r) {
                    int rowi = mg * 16 + quad * 4 + r;
                    float den = lsum[rowi] + lsum[32 + rowi] + lsum[64 + rowi] + lsum[96 + rowi];
                    Dpart[(half * 4 + h) * N_NODES + i0 + rowi] = den;
                }
        }
    }
    #undef RED_WRITE
    #undef RED_ADD
}

// ---------------------------------------------------------------------------
// Kernel 6: merge halves, normalize, elu, store (dual-dtype out).
// ---------------------------------------------------------------------------
__global__ __launch_bounds__(256) void merge_k(const float* __restrict__ Npart,
                                               const float* __restrict__ Dpart,
                                               void* __restrict__ out,
                                               const int* __restrict__ flag)
{
    const int f32 = *flag;
    const size_t e4 = ((size_t)blockIdx.x * 256 + threadIdx.x) * 4;
    const int i = (int)(e4 >> 9);
    const int c = (int)(e4 & 511);
    const int h = c >> 7;
    const float4v n0 = *(const float4v*)(Npart + e4);
    const float4v n1 = *(const float4v*)(Npart + (size_t)N_NODES * ODIM + e4);
    const float den = Dpart[h * N_NODES + i] + Dpart[(4 + h) * N_NODES + i];
    const float rinv = 1.0f / fmaxf(den, 1e-37f);
    const float C1 = 1.44269504f;
    float o[4];
    #pragma unroll
    for (int k = 0; k < 4; ++k) {
        float v = (n0[k] + n1[k]) * rinv;
        float e = __builtin_amdgcn_exp2f(v * C1) - 1.0f;
        o[k] = (v > 0.f) ? v : e;
    }
    if (f32) {
        float4v ov;
        #pragma unroll
        for (int k = 0; k < 4; ++k) ov[k] = o[k];
        *(float4v*)((float*)out + e4) = ov;
    } else {
        short4v ov;
        #pragma unroll
        for (int k = 0; k < 4; ++k) ov[k] = (short)f2bf_rne(o[k]);
        *(short4v*)((ushort_t*)out + e4) = ov;
    }
}

// ---------------------------------------------------------------------------
// Fallback single-pass attention (R5 structure) if ws too small for partials.
// ---------------------------------------------------------------------------
__global__ __launch_bounds__(256, 2) void attn_single_k(const ushort_t* __restrict__ WhT,
                                                        const unsigned* __restrict__ Apack,
                                                        const float* __restrict__ sl,
                                                        const float* __restrict__ sr,
                                                        void* __restrict__ out,
                                                        const int* __restrict__ flag)
{
    __shared__ float    srs[N_NODES];
    __shared__ unsigned mbuf[32][128];
    __shared__ float    red[2][32][128];
    __shared__ float    lsum[4][32];

    const int f32  = *flag;
    const int tid  = threadIdx.x;
    const int lane = tid & 63;
    const int wq   = tid >> 6;
    const int quad = lane >> 4;
    const int l15  = lane & 15;
    const int h    = blockIdx.x & 3;
    const int i0   = (blockIdx.x >> 2) << 5;

    for (int j = tid; j < N_NODES; j += 256) srs[j] = sr[h * N_NODES + j];
    for (int t = tid; t < 32 * 128; t += 256) {
        int r = t >> 7, c = t & 127;
        mbuf[r][c] = Apack[(size_t)(i0 + r) * 128 + c];
    }
    const float slv0 = sl[h * N_NODES + i0 + l15];
    const float slv1 = sl[h * N_NODES + i0 + 16 + l15];
    __syncthreads();

    const float C1 = 1.44269504f;
    const float C2 = 0.2f * 1.44269504f;

    float4v acc[2][8];
    #pragma unroll
    for (int mg = 0; mg < 2; ++mg)
        #pragma unroll
        for (int nt = 0; nt < 8; ++nt)
            #pragma unroll
            for (int e = 0; e < 4; ++e) acc[mg][nt][e] = 0.f;
    float lacc0 = 0.f, lacc1 = 0.f;

    const ushort_t* vb = WhT + (size_t)(h * DK + l15) * N_NODES + wq * 1024 + quad * 8;

    #pragma unroll 1
    for (int it = 0; it < 16; ++it) {
        const int jl = it * 64;
        const int j0 = wq * 1024 + jl;
        const int mc = j0 >> 5;

        short8 bf[8][2];
        #pragma unroll
        for (int nt = 0; nt < 8; ++nt) {
            bf[nt][0] = *(const short8*)(vb + (size_t)nt * 16 * N_NODES + jl);
            bf[nt][1] = *(const short8*)(vb + (size_t)nt * 16 * N_NODES + jl + 32);
        }

        const unsigned wa0 = mbuf[l15][mc],      wa1 = mbuf[l15][mc + 1];
        const unsigned wb0 = mbuf[16 + l15][mc], wb1 = mbuf[16 + l15][mc + 1];

        short8 pf0[2], pf1[2];
        #pragma unroll
        for (int s = 0; s < 2; ++s) {
            const float* sp = &srs[j0 + s * 32 + quad * 8];
            const float4v s0 = *(const float4v*)sp;
            const float4v s1 = *(const float4v*)(sp + 4);
            const unsigned wa = s ? wa1 : wa0;
            const unsigned wb = s ? wb1 : wb0;
            #pragma unroll
            for (int jj = 0; jj < 8; ++jj) {
                float srj = (jj < 4) ? s0[jj] : s1[jj - 4];
                int bit = quad * 8 + jj;
                float x0 = slv0 + srj;
                float t0 = fmaxf(x0 * C1, x0 * C2);
                t0 = ((wa >> bit) & 1u) ? t0 : -1e30f;
                float p0 = __builtin_amdgcn_exp2f(t0);
                ushort_t h0 = (ushort_t)(__float_as_uint(p0) >> 16);
                lacc0 += bf2f(h0);
                pf0[s][jj] = (short)h0;
                float x1 = slv1 + srj;
                float t1 = fmaxf(x1 * C1, x1 * C2);
                t1 = ((wb >> bit) & 1u) ? t1 : -1e30f;
                float p1 = __builtin_amdgcn_exp2f(t1);
                ushort_t h1 = (ushort_t)(__float_as_uint(p1) >> 16);
                lacc1 += bf2f(h1);
                pf1[s][jj] = (short)h1;
            }
        }

        #pragma unroll
        for (int nt = 0; nt < 8; ++nt) {
            acc[0][nt] = __builtin_amdgcn_mfma_f32_16x16x32_bf16(pf0[0], bf[nt][0], acc[0][nt], 0, 0, 0);
            acc[0][nt] = __builtin_amdgcn_mfma_f32_16x16x32_bf16(pf0[1], bf[nt][1], acc[0][nt], 0, 0, 0);
            acc[1][nt] = __builtin_amdgcn_mfma_f32_16x16x32_bf16(pf1[0], bf[nt][0], acc[1][nt], 0, 0, 0);
            acc[1][nt] = __builtin_amdgcn_mfma_f32_16x16x32_bf16(pf1[1], bf[nt][1], acc[1][nt], 0, 0, 0);
        }
    }

    lacc0 += __shfl_xor(lacc0, 16);
    lacc0 += __shfl_xor(lacc0, 32);
    lacc1 += __shfl_xor(lacc1, 16);
    lacc1 += __shfl_xor(lacc1, 32);
    if (lane < 16) {
        lsum[wq][l15]      = lacc0;
        lsum[wq][16 + l15] = lacc1;
    }
    if (wq >= 2) {
        #pragma unroll
        for (int mg = 0; mg < 2; ++mg)
            #pragma unroll
            for (int nt = 0; nt < 8; ++nt)
                #pragma unroll
                for (int r = 0; r < 4; ++r)
                    red[wq - 2][mg * 16 + quad * 4 + r][nt * 16 + l15] = acc[mg][nt][r];
    }
    __syncthreads();
    if (wq < 2) {
        #pragma unroll
        for (int mg = 0; mg < 2; ++mg)
            #pragma unroll
            for (int nt = 0; nt < 8; ++nt)
                #pragma unroll
                for (int r = 0; r < 4; ++r)
                    acc[mg][nt][r] += red[wq][mg * 16 + quad * 4 + r][nt * 16 + l15];
    }
    __syncthreads();
    if (wq == 1) {
        #pragma unroll
        for (int mg = 0; mg < 2; ++mg)
            #pragma unroll
            for (int nt = 0; nt < 8; ++nt)
                #pragma unroll
                for (int r = 0; r < 4; ++r)
                    red[0][mg * 16 + quad * 4 + r][nt * 16 + l15] = acc[mg][nt][r];
    }
    __syncthreads();
    if (wq == 0) {
        #pragma unroll
        for (int mg = 0; mg < 2; ++mg) {
            float linv[4];
            #pragma unroll
            for (int r = 0; r < 4; ++r) {
                int rowi = mg * 16 + quad * 4 + r;
                float den = lsum[0][rowi] + lsum[1][rowi] + lsum[2][rowi] + lsum[3][rowi];
                linv[r] = 1.0f / fmaxf(den, 1e-37f);
            }
            #pragma unroll
            for (int nt = 0; nt < 8; ++nt)
                #pragma unroll
                for (int r = 0; r < 4; ++r) {
                    int rowi = mg * 16 + quad * 4 + r;
                    float v = (acc[mg][nt][r] + red[0][rowi][nt * 16 + l15]) * linv[r];
                    float e = __builtin_amdgcn_exp2f(v * C1) - 1.0f;
                    float o = (v > 0.f) ? v : e;
                    size_t oidx = (size_t)(i0 + rowi) * ODIM + h * DK + nt * 16 + l15;
                    if (f32) ((float*)out)[oidx] = o;
                    else     ((ushort_t*)out)[oidx] = f2bf_rne(o);
                }
        }
    }
}

// ---------------------------------------------------------------------------
extern "C" void kernel_launch(void* const* d_in, const int* in_sizes, int n_in,
                              void* d_out, int out_size, void* d_ws, size_t ws_size,
                              hipStream_t stream)
{
    const void* H  = d_in[0];
    const int*  A  = (const int*)d_in[1];
    const void* W  = d_in[2];
    const void* al = d_in[3];
    const void* ar = d_in[4];

    if (ws_size < (7u << 20)) return;

    char* ws = (char*)d_ws;
    ushort_t* WhT   = (ushort_t*)ws;                                    // 4 MB
    unsigned long long* Apack = (unsigned long long*)(ws + (4u << 20)); // 2 MB
    ushort_t* WT    = (ushort_t*)(ws + (6u << 20));                     // 512 KB
    float*    sl    = (float*)(ws + (6u << 20) + (512u << 10));         // 64 KB
    float*    sr    = (float*)(ws + (6u << 20) + (576u << 10));         // 64 KB
    int*      flag  = (int*)(ws + (6u << 20) + (640u << 10));           // 4 B
    float*    Npart = (float*)(ws + (12u << 20));                       // 16 MB
    float*    Dpart = (float*)(ws + (28u << 20));                       // 128 KB
    const bool have_split = ws_size >= (29u << 20);

    pack_mask_k    <<<16384, 256, 0, stream>>>(A, Apack, (const ushort_t*)H, flag);
    transpose_w_k  <<<64,    256, 0, stream>>>(W, WT, flag);
    gemm_wht_dual_k<<<512,   256, 0, stream>>>(H, WT, WhT, flag);
    slsr_k         <<<64,    256, 0, stream>>>(WhT, al, ar, sl, sr, flag);
    if (have_split) {
        attn_split_k<<<1024, 256, 0, stream>>>(WhT, (const unsigned*)Apack, sl, sr, Npart, Dpart);
        merge_k     <<<2048, 256, 0, stream>>>(Npart, Dpart, (void*)d_out, flag);
    } else {
        attn_single_k<<<512, 256, 0, stream>>>(WhT, (const unsigned*)Apack, sl, sr, (void*)d_out, flag);
    }
}

// Round 4
// 181.098 us; speedup vs baseline: 1.4936x; 1.4936x over previous
//
#include <hip/hip_runtime.h>

typedef unsigned short ushort_t;
typedef __attribute__((ext_vector_type(8)))  short  short8;
typedef __attribute__((ext_vector_type(4)))  short  short4v;
typedef __attribute__((ext_vector_type(4)))  float  float4v;
typedef __attribute__((ext_vector_type(4)))  int    int4v;

#define N_NODES 4096
#define NHEADS  4
#define DK      128
#define ODIM    512
#define KDIM    512

__device__ __forceinline__ float bf2f(ushort_t u) {
    return __uint_as_float(((unsigned)u) << 16);
}
__device__ __forceinline__ ushort_t f2bf_rne(float f) {
    unsigned u = __float_as_uint(f);
    u += 0x7fffu + ((u >> 16) & 1u);
    return (ushort_t)(u >> 16);
}

// ---------------------------------------------------------------------------
// Kernel 1 (fused): mask bit-pack + dtype flag + W transpose + sl/sr zeroing.
//  - all 16384 blocks: pack 1024 ints of A via int4 loads + 16-lane shfl-OR.
//  - block 0: global dtype flag (for gemm/merge/attn_single).
//  - blocks 0..63: WT[n][k] = W[k][n] as bf16, with block-LOCAL dtype
//    detection (cannot read the global flag written by block 0 — race).
//  - blocks 64..95: zero sl/sr (gemm accumulates them via atomicAdd).
// ---------------------------------------------------------------------------
__global__ __launch_bounds__(256) void pack_mask_k(const int* __restrict__ A,
                                                   unsigned long long* __restrict__ P,
                                                   const ushort_t* __restrict__ Hraw,
                                                   int* __restrict__ flag,
                                                   const void* __restrict__ W,
                                                   ushort_t* __restrict__ WT,
                                                   float* __restrict__ sl,
                                                   float* __restrict__ sr)
{
    __shared__ ushort_t lt[64][72];
    __shared__ int dcnt[4];
    const int tid = threadIdx.x;
    const int bx  = blockIdx.x;

    if (bx == 0 && tid < 64) {
        const int lane = tid;
        int cnt = 0;
        #pragma unroll
        for (int s = 0; s < 16; ++s) {
            ushort_t v = Hraw[(lane * 16 + s) * 2];
            int e = (v >> 7) & 0xFF;
            cnt += (((e >= 90) && (e <= 140)) || (v == 0)) ? 1 : 0;
        }
        #pragma unroll
        for (int off = 32; off; off >>= 1) cnt += __shfl_down(cnt, off);
        if (lane == 0) *flag = (cnt < 768) ? 1 : 0;
    }

    // ---- mask pack (all blocks) ----
    {
        const int lane  = tid & 63;
        const int flat4 = bx * 256 + tid;             // index in units of int4
        const int row   = flat4 >> 10;                // (flat4*4) >> 12
        const int col0  = (flat4 << 2) & 4095;
        const int4v a   = ((const int4v*)A)[flat4];
        unsigned nib = 0;
        #pragma unroll
        for (int j = 0; j < 4; ++j)
            nib |= ((a[j] != 0) || (row == col0 + j)) ? (1u << j) : 0u;
        unsigned long long v = (unsigned long long)nib << ((lane & 15) * 4);
        v |= __shfl_xor(v, 1);
        v |= __shfl_xor(v, 2);
        v |= __shfl_xor(v, 4);
        v |= __shfl_xor(v, 8);
        if ((lane & 15) == 0) P[flat4 >> 4] = v;
    }

    // ---- zero sl/sr (blocks 64..95): 8192 threads x one float4 ----
    if (bx >= 64 && bx < 96) {
        const int idx = (bx - 64) * 256 + tid;        // 0..8191
        float4v z;
        #pragma unroll
        for (int e = 0; e < 4; ++e) z[e] = 0.f;
        if (idx < 4096) ((float4v*)sl)[idx] = z;
        else            ((float4v*)sr)[idx - 4096] = z;
    }

    // ---- W transpose (blocks 0..63) ----
    if (bx < 64) {
        // block-local dtype detection (same 1024 samples as the global flag)
        int cnt = 0;
        #pragma unroll
        for (int s = 0; s < 4; ++s) {
            ushort_t v = Hraw[(tid * 4 + s) * 2];
            int e = (v >> 7) & 0xFF;
            cnt += (((e >= 90) && (e <= 140)) || (v == 0)) ? 1 : 0;
        }
        #pragma unroll
        for (int off = 32; off; off >>= 1) cnt += __shfl_down(cnt, off);
        if ((tid & 63) == 0) dcnt[tid >> 6] = cnt;
        __syncthreads();
        const int f32 = (dcnt[0] + dcnt[1] + dcnt[2] + dcnt[3]) < 768;

        const int ti = bx >> 3, tj = bx & 7;
        const int r = tid >> 2, c2 = tid & 3;
        const size_t eo = (size_t)(ti * 64 + r) * KDIM + tj * 64 + c2 * 16;
        if (f32) {
            const float4v* src = (const float4v*)((const float*)W + eo);
            float4v f0 = src[0], f1 = src[1], f2 = src[2], f3 = src[3];
            #pragma unroll
            for (int e = 0; e < 4; ++e) {
                lt[r][c2 * 16 +  0 + e] = f2bf_rne(f0[e]);
                lt[r][c2 * 16 +  4 + e] = f2bf_rne(f1[e]);
                lt[r][c2 * 16 +  8 + e] = f2bf_rne(f2[e]);
                lt[r][c2 * 16 + 12 + e] = f2bf_rne(f3[e]);
            }
        } else {
            const short8* src = (const short8*)((const ushort_t*)W + eo);
            short8 v0 = src[0];
            short8 v1 = src[1];
            *(short8*)&lt[r][c2 * 16]     = v0;
            *(short8*)&lt[r][c2 * 16 + 8] = v1;
        }
        __syncthreads();
        #pragma unroll
        for (int itr = 0; itr < 2; ++itr) {
            int idx = itr * 256 + tid;
            int n = idx >> 3, c = idx & 7;
            short8 vv;
            #pragma unroll
            for (int e = 0; e < 8; ++e) vv[e] = (short)lt[c * 8 + e][n];
            *(short8*)(WT + (size_t)(tj * 64 + n) * KDIM + ti * 64 + c * 8) = vv;
        }
    }
}

// ---------------------------------------------------------------------------
// Kernel 2 (fused): WhT[n][i] = (H @ W)[i][n] + sl/sr partial accumulation.
// XCD mapping: bm = bx&63 so all 8 bn-blocks of one H-panel land on the same
// XCD -> H fetched once from HBM.  Epilogue reuses the lt tile (already the
// bf16 WhT values) to compute partial sl/sr over this block's 64 d-values:
// 4 threads per output row, 16 d each, 4-lane shfl reduce, one atomicAdd per
// (row, sl/sr) — replaces the slsr_k kernel and its 4 MB WhT re-read.
// ---------------------------------------------------------------------------
__global__ __launch_bounds__(256) void gemm_wht_dual_k(const void* __restrict__ H,
                                                       const ushort_t* __restrict__ WT,
                                                       ushort_t* __restrict__ WhT,
                                                       const int* __restrict__ flag,
                                                       const void* __restrict__ al,
                                                       const void* __restrict__ ar,
                                                       float* __restrict__ sl,
                                                       float* __restrict__ sr)
{
    __shared__ ushort_t lt[64][72];
    const int f32 = *flag;
    const int tid  = threadIdx.x;
    const int lane = tid & 63;
    const int wid  = tid >> 6;
    const int quad = lane >> 4;
    const int l15  = lane & 15;
    const int bm = blockIdx.x & 63, bn = blockIdx.x >> 6;
    const int i0 = bm * 64, n0 = bn * 64;

    const size_t aoff = (size_t)(i0 + wid * 16 + l15) * KDIM + quad * 8;
    const short8* bp0 = (const short8*)(WT + (size_t)(n0 +  0 + l15) * KDIM) + quad;
    const short8* bp1 = (const short8*)(WT + (size_t)(n0 + 16 + l15) * KDIM) + quad;
    const short8* bp2 = (const short8*)(WT + (size_t)(n0 + 32 + l15) * KDIM) + quad;
    const short8* bp3 = (const short8*)(WT + (size_t)(n0 + 48 + l15) * KDIM) + quad;

    float4v acc0, acc1, acc2, acc3;
    #pragma unroll
    for (int e = 0; e < 4; ++e) { acc0[e] = 0.f; acc1[e] = 0.f; acc2[e] = 0.f; acc3[e] = 0.f; }

    #pragma unroll 4
    for (int k8 = 0; k8 < 64; k8 += 4) {
        short8 a;
        if (f32) {
            const float4v* fp = (const float4v*)((const float*)H + aoff + (size_t)k8 * 8);
            float4v x0 = fp[0], x1 = fp[1];
            #pragma unroll
            for (int e = 0; e < 4; ++e) {
                a[e]     = (short)f2bf_rne(x0[e]);
                a[4 + e] = (short)f2bf_rne(x1[e]);
            }
        } else {
            a = *(const short8*)((const ushort_t*)H + aoff + (size_t)k8 * 8);
        }
        acc0 = __builtin_amdgcn_mfma_f32_16x16x32_bf16(a, bp0[k8], acc0, 0, 0, 0);
        acc1 = __builtin_amdgcn_mfma_f32_16x16x32_bf16(a, bp1[k8], acc1, 0, 0, 0);
        acc2 = __builtin_amdgcn_mfma_f32_16x16x32_bf16(a, bp2[k8], acc2, 0, 0, 0);
        acc3 = __builtin_amdgcn_mfma_f32_16x16x32_bf16(a, bp3[k8], acc3, 0, 0, 0);
    }

    #pragma unroll
    for (int r = 0; r < 4; ++r) {
        int m = wid * 16 + quad * 4 + r;
        lt[ 0 + l15][m] = f2bf_rne(acc0[r]);
        lt[16 + l15][m] = f2bf_rne(acc1[r]);
        lt[32 + l15][m] = f2bf_rne(acc2[r]);
        lt[48 + l15][m] = f2bf_rne(acc3[r]);
    }
    __syncthreads();
    #pragma unroll
    for (int itr = 0; itr < 2; ++itr) {
        int idx = itr * 256 + tid;
        int n = idx >> 3, c = idx & 7;
        short8 v = *(const short8*)&lt[n][c * 8];
        *(short8*)(WhT + (size_t)(n0 + n) * N_NODES + i0 + c * 8) = v;
    }

    // ---- fused slsr partials over this block's 64 d-values ----
    {
        const int h2 = n0 >> 7;          // head
        const int d0 = n0 & 127;         // d offset within head
        const int m  = tid >> 2;         // output row = i0 + m
        const int part = tid & 3;
        float psl = 0.f, psr = 0.f;
        #pragma unroll
        for (int k = 0; k < 16; ++k) {
            int n = part * 16 + k;
            float wv = bf2f(lt[n][m]);
            float av = f32 ? ((const float*)al)[h2 * DK + d0 + n]
                           : bf2f(((const ushort_t*)al)[h2 * DK + d0 + n]);
            float bv = f32 ? ((const float*)ar)[h2 * DK + d0 + n]
                           : bf2f(((const ushort_t*)ar)[h2 * DK + d0 + n]);
            psl += wv * av;
            psr += wv * bv;
        }
        psl += __shfl_down(psl, 2); psl += __shfl_down(psl, 1);
        psr += __shfl_down(psr, 2); psr += __shfl_down(psr, 1);
        if (part == 0) {
            atomicAdd(&sl[h2 * N_NODES + i0 + m], psl);
            atomicAdd(&sr[h2 * N_NODES + i0 + m], psr);
        }
    }
}

// ---------------------------------------------------------------------------
// Kernel 3 = v12 attn (proven 55.5 us): global_load_lds double-buffered DMA,
// vmcnt(8) counted drain, mbuf XOR column swizzle, C1-prescaled sl/sr,
// MFMA-ones denominator, fp32 partials + merge_k.
// v13 post-mortem: reg-dbuf at (256,3) spilled (VGPR cap ~168 < ~165 live +
// addressing; WRITE_SIZE 16.5->55.9 MB scratch).  The LDS DMA pipeline is
// the correct prefetch engine at this occupancy.
// ---------------------------------------------------------------------------
__global__ __launch_bounds__(256, 2) void attn_split_k(const ushort_t* __restrict__ WhT,
                                                       const unsigned* __restrict__ Apack,
                                                       const float* __restrict__ sl,
                                                       const float* __restrict__ sr,
                                                       float* __restrict__ Npart,
                                                       float* __restrict__ Dpart)
{
    __shared__ char smem[81920] __attribute__((aligned(16)));
    float*    srs  = (float*)smem;                          // 2048 fp32, 8 KB
    unsigned (*mbuf)[64] = (unsigned (*)[64])(smem + 8192); // 32x64, 8 KB (XOR-swizzled cols)
    ushort_t* vbuf = (ushort_t*)(smem + 16384);             // 4 waves x 2 x 4096

    const int tid  = threadIdx.x;
    const int lane = tid & 63;
    const int wq   = tid >> 6;               // j-quarter of the half
    const int quad = lane >> 4;
    const int l15  = lane & 15;
    const int bx   = blockIdx.x;
    const int half = bx & 1;
    const int h    = (bx >> 1) & 3;
    const int i0   = (bx >> 3) << 5;         // 32-row tile
    const int jbase = half << 11;            // 0 or 2048

    const float C1 = 1.44269504f;             // log2(e)

    for (int j = tid; j < 2048; j += 256) srs[j] = sr[h * N_NODES + jbase + j] * C1;
    for (int t = tid; t < 32 * 64; t += 256) {
        int r = t >> 6, c = t & 63;
        mbuf[r][c ^ r] = Apack[(size_t)(i0 + r) * 128 + (half << 6) + c];
    }
    const float slv0 = sl[h * N_NODES + i0 + l15] * C1;
    const float slv1 = sl[h * N_NODES + i0 + 16 + l15] * C1;
    __syncthreads();                          // staging done; no more loop barriers

    float4v acc[2][8];
    #pragma unroll
    for (int mg = 0; mg < 2; ++mg)
        #pragma unroll
        for (int nt = 0; nt < 8; ++nt)
            #pragma unroll
            for (int e = 0; e < 4; ++e) acc[mg][nt][e] = 0.f;
    float4v accden0, accden1;
    #pragma unroll
    for (int e = 0; e < 4; ++e) { accden0[e] = 0.f; accden1[e] = 0.f; }

    short8 ones;
    #pragma unroll
    for (int e = 0; e < 8; ++e) ones[e] = (short)0x3F80;   // bf16 1.0

    // DMA: lane L -> rows q*16 + (L>>2); LDS slot L&3; global chunk (L&3)^((L>>3)&3)
    // => row r slot s holds global chunk s^((r>>1)&3).
    const int Lrow = lane >> 2;
    const int gch  = (lane & 3) ^ ((lane >> 3) & 3);
    const ushort_t* gdma = WhT + (size_t)(h * DK + Lrow) * N_NODES + jbase + gch * 8;

    #define DMA_WIN(CUR, JW)                                                           \
        {   ushort_t* ld_ = vbuf + wq * 8192 + (CUR) * 4096;                           \
            const ushort_t* g_ = gdma + (JW);                                          \
            _Pragma("unroll")                                                          \
            for (int q_ = 0; q_ < 8; ++q_)                                             \
                __builtin_amdgcn_global_load_lds(                                      \
                    (const __attribute__((address_space(1))) void*)(g_ + (size_t)q_ * 16 * N_NODES), \
                    (__attribute__((address_space(3))) void*)(ld_ + q_ * 512),         \
                    16, 0, 0);                                                         \
        }

    DMA_WIN(0, wq * 512)
    DMA_WIN(1, wq * 512 + 32)

    const int so = (quad ^ ((l15 >> 1) & 3)) * 8;   // swizzled read slot (2-way, free)

    #pragma unroll 1
    for (int it = 0; it < 16; ++it) {
        const int cur = it & 1;
        const int jl  = wq * 512 + it * 32;   // local j within the half
        const int mc  = jl >> 5;

        const unsigned wa = mbuf[l15][mc ^ l15];
        const unsigned wb = mbuf[16 + l15][mc ^ (16 + l15)];
        const float4v s0 = *(const float4v*)&srs[jl + quad * 8];
        const float4v s1 = *(const float4v*)&srs[jl + quad * 8 + 4];

        short8 pf0, pf1;
        #pragma unroll
        for (int jj = 0; jj < 8; ++jj) {
            float srj = (jj < 4) ? s0[jj] : s1[jj - 4];
            int bit = quad * 8 + jj;
            float x0 = slv0 + srj;                       // already *C1
            float t0 = fmaxf(x0, x0 * 0.2f);
            t0 = ((wa >> bit) & 1u) ? t0 : -1e30f;
            pf0[jj] = (short)(ushort_t)(__float_as_uint(__builtin_amdgcn_exp2f(t0)) >> 16);
            float x1 = slv1 + srj;
            float t1 = fmaxf(x1, x1 * 0.2f);
            t1 = ((wb >> bit) & 1u) ? t1 : -1e30f;
            pf1[jj] = (short)(ushort_t)(__float_as_uint(__builtin_amdgcn_exp2f(t1)) >> 16);
        }

        if (it == 15) { asm volatile("s_waitcnt vmcnt(0)" ::: "memory"); }
        else          { asm volatile("s_waitcnt vmcnt(8)" ::: "memory"); }

        const ushort_t* vB = vbuf + wq * 8192 + cur * 4096;
        #pragma unroll
        for (int nt = 0; nt < 8; ++nt) {
            short8 b = *(const short8*)(vB + (nt * 16 + l15) * 32 + so);
            acc[0][nt] = __builtin_amdgcn_mfma_f32_16x16x32_bf16(pf0, b, acc[0][nt], 0, 0, 0);
            acc[1][nt] = __builtin_amdgcn_mfma_f32_16x16x32_bf16(pf1, b, acc[1][nt], 0, 0, 0);
        }
        accden0 = __builtin_amdgcn_mfma_f32_16x16x32_bf16(pf0, ones, accden0, 0, 0, 0);
        accden1 = __builtin_amdgcn_mfma_f32_16x16x32_bf16(pf1, ones, accden1, 0, 0, 0);

        if (it < 14) DMA_WIN(cur, wq * 512 + (it + 2) * 32)
    }
    #undef DMA_WIN

    // ---- epilogue: overlay red/lsum onto the V region (all DMAs drained) ----
    float* red  = (float*)(smem + 16384);     // 32 x 128 fp32
    float* lsum = (float*)(smem + 32768);     // 4 x 32 fp32
    __syncthreads();

    if (l15 == 0) {
        #pragma unroll
        for (int r = 0; r < 4; ++r) {
            lsum[wq * 32 + quad * 4 + r]      = accden0[r];
            lsum[wq * 32 + 16 + quad * 4 + r] = accden1[r];
        }
    }
    #define RED_WRITE                                                                \
        { _Pragma("unroll")                                                          \
          for (int mg = 0; mg < 2; ++mg)                                             \
            _Pragma("unroll")                                                        \
            for (int nt = 0; nt < 8; ++nt)                                           \
              _Pragma("unroll")                                                      \
              for (int r = 0; r < 4; ++r)                                            \
                red[(mg * 16 + quad * 4 + r) * 128 + nt * 16 + l15] = acc[mg][nt][r]; }
    #define RED_ADD                                                                 \
        { _Pragma("unroll")                                                          \
          for (int mg = 0; mg < 2; ++mg)                                             \
            _Pragma("unroll")                                                        \
            for (int nt = 0; nt < 8; ++nt)                                           \
              _Pragma("unroll")                                                      \
              for (int r = 0; r < 4; ++r)                                            \
                acc[mg][nt][r] += red[(mg * 16 + quad * 4 + r) * 128 + nt * 16 + l15]; }

    if (wq == 1) RED_WRITE
    __syncthreads();
    if (wq == 0) RED_ADD
    __syncthreads();
    if (wq == 3) RED_WRITE
    __syncthreads();
    if (wq == 2) RED_ADD
    __syncthreads();
    if (wq == 2) RED_WRITE
    __syncthreads();
    if (wq == 0) {
        RED_ADD
        float* Np = Npart + (size_t)half * N_NODES * ODIM;
        #pragma unroll
        for (int mg = 0; mg < 2; ++mg)
            #pragma unroll
            for (int nt = 0; nt < 8; ++nt)
                #pragma unroll
                for (int r = 0; r < 4; ++r) {
                    int rowi = mg * 16 + quad * 4 + r;
                    Np[(size_t)(i0 + rowi) * ODIM + h * DK + nt * 16 + l15] = acc[mg][nt][r];
                }
        if (l15 == 0) {
            #pragma unroll
            for (int mg = 0; mg < 2; ++mg)
                #pragma unroll
                for (int r = 0; r < 4; ++r) {
                    int rowi = mg * 16 + quad * 4 + r;
                    float den = lsum[rowi] + lsum[32 + rowi] + lsum[64 + rowi] + lsum[96 + rowi];
                    Dpart[(half * 4 + h) * N_NODES + i0 + rowi] = den;
                }
        }
    }
    #undef RED_WRITE
    #undef RED_ADD
}

// ---------------------------------------------------------------------------
// Kernel 4: merge halves, normalize, elu, store (dual-dtype out).
// ---------------------------------------------------------------------------
__global__ __launch_bounds__(256) void merge_k(const float* __restrict__ Npart,
                                               const float* __restrict__ Dpart,
                                               void* __restrict__ out,
                                               const int* __restrict__ flag)
{
    const int f32 = *flag;
    const size_t e4 = ((size_t)blockIdx.x * 256 + threadIdx.x) * 4;
    const int i = (int)(e4 >> 9);
    const int c = (int)(e4 & 511);
    const int h = c >> 7;
    const float4v n0 = *(const float4v*)(Npart + e4);
    const float4v n1 = *(const float4v*)(Npart + (size_t)N_NODES * ODIM + e4);
    const float den = Dpart[h * N_NODES + i] + Dpart[(4 + h) * N_NODES + i];
    const float rinv = 1.0f / fmaxf(den, 1e-37f);
    const float C1 = 1.44269504f;
    float o[4];
    #pragma unroll
    for (int k = 0; k < 4; ++k) {
        float v = (n0[k] + n1[k]) * rinv;
        float e = __builtin_amdgcn_exp2f(v * C1) - 1.0f;
        o[k] = (v > 0.f) ? v : e;
    }
    if (f32) {
        float4v ov;
        #pragma unroll
        for (int k = 0; k < 4; ++k) ov[k] = o[k];
        *(float4v*)((float*)out + e4) = ov;
    } else {
        short4v ov;
        #pragma unroll
        for (int k = 0; k < 4; ++k) ov[k] = (short)f2bf_rne(o[k]);
        *(short4v*)((ushort_t*)out + e4) = ov;
    }
}

// ---------------------------------------------------------------------------
// Fallback single-pass attention (R5 structure) if ws too small for partials.
// ---------------------------------------------------------------------------
__global__ __launch_bounds__(256, 2) void attn_single_k(const ushort_t* __restrict__ WhT,
                                                        const unsigned* __restrict__ Apack,
                                                        const float* __restrict__ sl,
                                                        const float* __restrict__ sr,
                                                        void* __restrict__ out,
                                                        const int* __restrict__ flag)
{
    __shared__ float    srs[N_NODES];
    __shared__ unsigned mbuf[32][128];
    __shared__ float    red[2][32][128];
    __shared__ float    lsum[4][32];

    const int f32  = *flag;
    const int tid  = threadIdx.x;
    const int lane = tid & 63;
    const int wq   = tid >> 6;
    const int quad = lane >> 4;
    const int l15  = lane & 15;
    const int h    = blockIdx.x & 3;
    const int i0   = (blockIdx.x >> 2) << 5;

    for (int j = tid; j < N_NODES; j += 256) srs[j] = sr[h * N_NODES + j];
    for (int t = tid; t < 32 * 128; t += 256) {
        int r = t >> 7, c = t & 127;
        mbuf[r][c] = Apack[(size_t)(i0 + r) * 128 + c];
    }
    const float slv0 = sl[h * N_NODES + i0 + l15];
    const float slv1 = sl[h * N_NODES + i0 + 16 + l15];
    __syncthreads();

    const float C1 = 1.44269504f;
    const float C2 = 0.2f * 1.44269504f;

    float4v acc[2][8];
    #pragma unroll
    for (int mg = 0; mg < 2; ++mg)
        #pragma unroll
        for (int nt = 0; nt < 8; ++nt)
            #pragma unroll
            for (int e = 0; e < 4; ++e) acc[mg][nt][e] = 0.f;
    float lacc0 = 0.f, lacc1 = 0.f;

    const ushort_t* vb = WhT + (size_t)(h * DK + l15) * N_NODES + wq * 1024 + quad * 8;

    #pragma unroll 1
    for (int it = 0; it < 16; ++it) {
        const int jl = it * 64;
        const int j0 = wq * 1024 + jl;
        const int mc = j0 >> 5;

        short8 bf[8][2];
        #pragma unroll
        for (int nt = 0; nt < 8; ++nt) {
            bf[nt][0] = *(const short8*)(vb + (size_t)nt * 16 * N_NODES + jl);
            bf[nt][1] = *(const short8*)(vb + (size_t)nt * 16 * N_NODES + jl + 32);
        }

        const unsigned wa0 = mbuf[l15][mc],      wa1 = mbuf[l15][mc + 1];
        const unsigned wb0 = mbuf[16 + l15][mc], wb1 = mbuf[16 + l15][mc + 1];

        short8 pf0[2], pf1[2];
        #pragma unroll
        for (int s = 0; s < 2; ++s) {
            const float* sp = &srs[j0 + s * 32 + quad * 8];
            const float4v s0 = *(const float4v*)sp;
            const float4v s1 = *(const float4v*)(sp + 4);
            const unsigned wa = s ? wa1 : wa0;
            const unsigned wb = s ? wb1 : wb0;
            #pragma unroll
            for (int jj = 0; jj < 8; ++jj) {
                float srj = (jj < 4) ? s0[jj] : s1[jj - 4];
                int bit = quad * 8 + jj;
                float x0 = slv0 + srj;
                float t0 = fmaxf(x0 * C1, x0 * C2);
                t0 = ((wa >> bit) & 1u) ? t0 : -1e30f;
                float p0 = __builtin_amdgcn_exp2f(t0);
                ushort_t h0 = (ushort_t)(__float_as_uint(p0) >> 16);
                lacc0 += bf2f(h0);
                pf0[s][jj] = (short)h0;
                float x1 = slv1 + srj;
                float t1 = fmaxf(x1 * C1, x1 * C2);
                t1 = ((wb >> bit) & 1u) ? t1 : -1e30f;
                float p1 = __builtin_amdgcn_exp2f(t1);
                ushort_t h1 = (ushort_t)(__float_as_uint(p1) >> 16);
                lacc1 += bf2f(h1);
                pf1[s][jj] = (short)h1;
            }
        }

        #pragma unroll
        for (int nt = 0; nt < 8; ++nt) {
            acc[0][nt] = __builtin_amdgcn_mfma_f32_16x16x32_bf16(pf0[0], bf[nt][0], acc[0][nt], 0, 0, 0);
            acc[0][nt] = __builtin_amdgcn_mfma_f32_16x16x32_bf16(pf0[1], bf[nt][1], acc[0][nt], 0, 0, 0);
            acc[1][nt] = __builtin_amdgcn_mfma_f32_16x16x32_bf16(pf1[0], bf[nt][0], acc[1][nt], 0, 0, 0);
            acc[1][nt] = __builtin_amdgcn_mfma_f32_16x16x32_bf16(pf1[1], bf[nt][1], acc[1][nt], 0, 0, 0);
        }
    }

    lacc0 += __shfl_xor(lacc0, 16);
    lacc0 += __shfl_xor(lacc0, 32);
    lacc1 += __shfl_xor(lacc1, 16);
    lacc1 += __shfl_xor(lacc1, 32);
    if (lane < 16) {
        lsum[wq][l15]      = lacc0;
        lsum[wq][16 + l15] = lacc1;
    }
    if (wq >= 2) {
        #pragma unroll
        for (int mg = 0; mg < 2; ++mg)
            #pragma unroll
            for (int nt = 0; nt < 8; ++nt)
                #pragma unroll
                for (int r = 0; r < 4; ++r)
                    red[wq - 2][mg * 16 + quad * 4 + r][nt * 16 + l15] = acc[mg][nt][r];
    }
    __syncthreads();
    if (wq < 2) {
        #pragma unroll
        for (int mg = 0; mg < 2; ++mg)
            #pragma unroll
            for (int nt = 0; nt < 8; ++nt)
                #pragma unroll
                for (int r = 0; r < 4; ++r)
                    acc[mg][nt][r] += red[wq][mg * 16 + quad * 4 + r][nt * 16 + l15];
    }
    __syncthreads();
    if (wq == 1) {
        #pragma unroll
        for (int mg = 0; mg < 2; ++mg)
            #pragma unroll
            for (int nt = 0; nt < 8; ++nt)
                #pragma unroll
                for (int r = 0; r < 4; ++r)
                    red[0][mg * 16 + quad * 4 + r][nt * 16 + l15] = acc[mg][nt][r];
    }
    __syncthreads();
    if (wq == 0) {
        #pragma unroll
        for (int mg = 0; mg < 2; ++mg) {
            float linv[4];
            #pragma unroll
            for (int r = 0; r < 4; ++r) {
                int rowi = mg * 16 + quad * 4 + r;
                float den = lsum[0][rowi] + lsum[1][rowi] + lsum[2][rowi] + lsum[3][rowi];
                linv[r] = 1.0f / fmaxf(den, 1e-37f);
            }
            #pragma unroll
            for (int nt = 0; nt < 8; ++nt)
                #pragma unroll
                for (int r = 0; r < 4; ++r) {
                    int rowi = mg * 16 + quad * 4 + r;
                    float v = (acc[mg][nt][r] + red[0][rowi][nt * 16 + l15]) * linv[r];
                    float e = __builtin_amdgcn_exp2f(v * C1) - 1.0f;
                    float o = (v > 0.f) ? v : e;
                    size_t oidx = (size_t)(i0 + rowi) * ODIM + h * DK + nt * 16 + l15;
                    if (f32) ((float*)out)[oidx] = o;
                    else     ((ushort_t*)out)[oidx] = f2bf_rne(o);
                }
        }
    }
}

// ---------------------------------------------------------------------------
extern "C" void kernel_launch(void* const* d_in, const int* in_sizes, int n_in,
                              void* d_out, int out_size, void* d_ws, size_t ws_size,
                              hipStream_t stream)
{
    const void* H  = d_in[0];
    const int*  A  = (const int*)d_in[1];
    const void* W  = d_in[2];
    const void* al = d_in[3];
    const void* ar = d_in[4];

    if (ws_size < (7u << 20)) return;

    char* ws = (char*)d_ws;
    ushort_t* WhT   = (ushort_t*)ws;                                    // 4 MB
    unsigned long long* Apack = (unsigned long long*)(ws + (4u << 20)); // 2 MB
    ushort_t* WT    = (ushort_t*)(ws + (6u << 20));                     // 512 KB
    float*    sl    = (float*)(ws + (6u << 20) + (512u << 10));         // 64 KB
    float*    sr    = (float*)(ws + (6u << 20) + (576u << 10));         // 64 KB
    int*      flag  = (int*)(ws + (6u << 20) + (640u << 10));           // 4 B
    float*    Npart = (float*)(ws + (12u << 20));                       // 16 MB
    float*    Dpart = (float*)(ws + (28u << 20));                       // 128 KB
    const bool have_split = ws_size >= (29u << 20);

    pack_mask_k    <<<16384, 256, 0, stream>>>(A, Apack, (const ushort_t*)H, flag,
                                               W, WT, sl, sr);
    gemm_wht_dual_k<<<512,   256, 0, stream>>>(H, WT, WhT, flag, al, ar, sl, sr);
    if (have_split) {
        attn_split_k<<<1024, 256, 0, stream>>>(WhT, (const unsigned*)Apack, sl, sr, Npart, Dpart);
        merge_k     <<<2048, 256, 0, stream>>>(Npart, Dpart, (void*)d_out, flag);
    } else {
        attn_single_k<<<512, 256, 0, stream>>>(WhT, (const unsigned*)Apack, sl, sr, (void*)d_out, flag);
    }
}

// Round 5
// 173.977 us; speedup vs baseline: 1.5548x; 1.0409x over previous
//
#include <hip/hip_runtime.h>

typedef unsigned short ushort_t;
typedef __attribute__((ext_vector_type(8)))  short  short8;
typedef __attribute__((ext_vector_type(4)))  short  short4v;
typedef __attribute__((ext_vector_type(4)))  float  float4v;
typedef __attribute__((ext_vector_type(4)))  int    int4v;

#define N_NODES 4096
#define NHEADS  4
#define DK      128
#define ODIM    512
#define KDIM    512

__device__ __forceinline__ float bf2f(ushort_t u) {
    return __uint_as_float(((unsigned)u) << 16);
}
__device__ __forceinline__ ushort_t f2bf_rne(float f) {
    unsigned u = __float_as_uint(f);
    u += 0x7fffu + ((u >> 16) & 1u);
    return (ushort_t)(u >> 16);
}

// ---------------------------------------------------------------------------
// Kernel 1 (fused): mask bit-pack + dtype flag + W transpose + sl/sr zeroing.
// ---------------------------------------------------------------------------
__global__ __launch_bounds__(256) void pack_mask_k(const int* __restrict__ A,
                                                   unsigned long long* __restrict__ P,
                                                   const ushort_t* __restrict__ Hraw,
                                                   int* __restrict__ flag,
                                                   const void* __restrict__ W,
                                                   ushort_t* __restrict__ WT,
                                                   float* __restrict__ sl,
                                                   float* __restrict__ sr)
{
    __shared__ ushort_t lt[64][72];
    __shared__ int dcnt[4];
    const int tid = threadIdx.x;
    const int bx  = blockIdx.x;

    if (bx == 0 && tid < 64) {
        const int lane = tid;
        int cnt = 0;
        #pragma unroll
        for (int s = 0; s < 16; ++s) {
            ushort_t v = Hraw[(lane * 16 + s) * 2];
            int e = (v >> 7) & 0xFF;
            cnt += (((e >= 90) && (e <= 140)) || (v == 0)) ? 1 : 0;
        }
        #pragma unroll
        for (int off = 32; off; off >>= 1) cnt += __shfl_down(cnt, off);
        if (lane == 0) *flag = (cnt < 768) ? 1 : 0;
    }

    // ---- mask pack (all blocks) ----
    {
        const int lane  = tid & 63;
        const int flat4 = bx * 256 + tid;             // index in units of int4
        const int row   = flat4 >> 10;                // (flat4*4) >> 12
        const int col0  = (flat4 << 2) & 4095;
        const int4v a   = ((const int4v*)A)[flat4];
        unsigned nib = 0;
        #pragma unroll
        for (int j = 0; j < 4; ++j)
            nib |= ((a[j] != 0) || (row == col0 + j)) ? (1u << j) : 0u;
        unsigned long long v = (unsigned long long)nib << ((lane & 15) * 4);
        v |= __shfl_xor(v, 1);
        v |= __shfl_xor(v, 2);
        v |= __shfl_xor(v, 4);
        v |= __shfl_xor(v, 8);
        if ((lane & 15) == 0) P[flat4 >> 4] = v;
    }

    // ---- zero sl/sr (blocks 64..95): 8192 threads x one float4 ----
    if (bx >= 64 && bx < 96) {
        const int idx = (bx - 64) * 256 + tid;        // 0..8191
        float4v z;
        #pragma unroll
        for (int e = 0; e < 4; ++e) z[e] = 0.f;
        if (idx < 4096) ((float4v*)sl)[idx] = z;
        else            ((float4v*)sr)[idx - 4096] = z;
    }

    // ---- W transpose (blocks 0..63) ----
    if (bx < 64) {
        // block-local dtype detection (same 1024 samples as the global flag)
        int cnt = 0;
        #pragma unroll
        for (int s = 0; s < 4; ++s) {
            ushort_t v = Hraw[(tid * 4 + s) * 2];
            int e = (v >> 7) & 0xFF;
            cnt += (((e >= 90) && (e <= 140)) || (v == 0)) ? 1 : 0;
        }
        #pragma unroll
        for (int off = 32; off; off >>= 1) cnt += __shfl_down(cnt, off);
        if ((tid & 63) == 0) dcnt[tid >> 6] = cnt;
        __syncthreads();
        const int f32 = (dcnt[0] + dcnt[1] + dcnt[2] + dcnt[3]) < 768;

        const int ti = bx >> 3, tj = bx & 7;
        const int r = tid >> 2, c2 = tid & 3;
        const size_t eo = (size_t)(ti * 64 + r) * KDIM + tj * 64 + c2 * 16;
        if (f32) {
            const float4v* src = (const float4v*)((const float*)W + eo);
            float4v f0 = src[0], f1 = src[1], f2 = src[2], f3 = src[3];
            #pragma unroll
            for (int e = 0; e < 4; ++e) {
                lt[r][c2 * 16 +  0 + e] = f2bf_rne(f0[e]);
                lt[r][c2 * 16 +  4 + e] = f2bf_rne(f1[e]);
                lt[r][c2 * 16 +  8 + e] = f2bf_rne(f2[e]);
                lt[r][c2 * 16 + 12 + e] = f2bf_rne(f3[e]);
            }
        } else {
            const short8* src = (const short8*)((const ushort_t*)W + eo);
            short8 v0 = src[0];
            short8 v1 = src[1];
            *(short8*)&lt[r][c2 * 16]     = v0;
            *(short8*)&lt[r][c2 * 16 + 8] = v1;
        }
        __syncthreads();
        #pragma unroll
        for (int itr = 0; itr < 2; ++itr) {
            int idx = itr * 256 + tid;
            int n = idx >> 3, c = idx & 7;
            short8 vv;
            #pragma unroll
            for (int e = 0; e < 8; ++e) vv[e] = (short)lt[c * 8 + e][n];
            *(short8*)(WT + (size_t)(tj * 64 + n) * KDIM + ti * 64 + c * 8) = vv;
        }
    }
}

// ---------------------------------------------------------------------------
// Kernel 2 (fused): WhT[n][i] = (H @ W)[i][n] + sl/sr partial accumulation.
// ---------------------------------------------------------------------------
__global__ __launch_bounds__(256) void gemm_wht_dual_k(const void* __restrict__ H,
                                                       const ushort_t* __restrict__ WT,
                                                       ushort_t* __restrict__ WhT,
                                                       const int* __restrict__ flag,
                                                       const void* __restrict__ al,
                                                       const void* __restrict__ ar,
                                                       float* __restrict__ sl,
                                                       float* __restrict__ sr)
{
    __shared__ ushort_t lt[64][72];
    const int f32 = *flag;
    const int tid  = threadIdx.x;
    const int lane = tid & 63;
    const int wid  = tid >> 6;
    const int quad = lane >> 4;
    const int l15  = lane & 15;
    const int bm = blockIdx.x & 63, bn = blockIdx.x >> 6;
    const int i0 = bm * 64, n0 = bn * 64;

    const size_t aoff = (size_t)(i0 + wid * 16 + l15) * KDIM + quad * 8;
    const short8* bp0 = (const short8*)(WT + (size_t)(n0 +  0 + l15) * KDIM) + quad;
    const short8* bp1 = (const short8*)(WT + (size_t)(n0 + 16 + l15) * KDIM) + quad;
    const short8* bp2 = (const short8*)(WT + (size_t)(n0 + 32 + l15) * KDIM) + quad;
    const short8* bp3 = (const short8*)(WT + (size_t)(n0 + 48 + l15) * KDIM) + quad;

    float4v acc0, acc1, acc2, acc3;
    #pragma unroll
    for (int e = 0; e < 4; ++e) { acc0[e] = 0.f; acc1[e] = 0.f; acc2[e] = 0.f; acc3[e] = 0.f; }

    #pragma unroll 4
    for (int k8 = 0; k8 < 64; k8 += 4) {
        short8 a;
        if (f32) {
            const float4v* fp = (const float4v*)((const float*)H + aoff + (size_t)k8 * 8);
            float4v x0 = fp[0], x1 = fp[1];
            #pragma unroll
            for (int e = 0; e < 4; ++e) {
                a[e]     = (short)f2bf_rne(x0[e]);
                a[4 + e] = (short)f2bf_rne(x1[e]);
            }
        } else {
            a = *(const short8*)((const ushort_t*)H + aoff + (size_t)k8 * 8);
        }
        acc0 = __builtin_amdgcn_mfma_f32_16x16x32_bf16(a, bp0[k8], acc0, 0, 0, 0);
        acc1 = __builtin_amdgcn_mfma_f32_16x16x32_bf16(a, bp1[k8], acc1, 0, 0, 0);
        acc2 = __builtin_amdgcn_mfma_f32_16x16x32_bf16(a, bp2[k8], acc2, 0, 0, 0);
        acc3 = __builtin_amdgcn_mfma_f32_16x16x32_bf16(a, bp3[k8], acc3, 0, 0, 0);
    }

    #pragma unroll
    for (int r = 0; r < 4; ++r) {
        int m = wid * 16 + quad * 4 + r;
        lt[ 0 + l15][m] = f2bf_rne(acc0[r]);
        lt[16 + l15][m] = f2bf_rne(acc1[r]);
        lt[32 + l15][m] = f2bf_rne(acc2[r]);
        lt[48 + l15][m] = f2bf_rne(acc3[r]);
    }
    __syncthreads();
    #pragma unroll
    for (int itr = 0; itr < 2; ++itr) {
        int idx = itr * 256 + tid;
        int n = idx >> 3, c = idx & 7;
        short8 v = *(const short8*)&lt[n][c * 8];
        *(short8*)(WhT + (size_t)(n0 + n) * N_NODES + i0 + c * 8) = v;
    }

    // ---- fused slsr partials over this block's 64 d-values ----
    {
        const int h2 = n0 >> 7;          // head
        const int d0 = n0 & 127;         // d offset within head
        const int m  = tid >> 2;         // output row = i0 + m
        const int part = tid & 3;
        float psl = 0.f, psr = 0.f;
        #pragma unroll
        for (int k = 0; k < 16; ++k) {
            int n = part * 16 + k;
            float wv = bf2f(lt[n][m]);
            float av = f32 ? ((const float*)al)[h2 * DK + d0 + n]
                           : bf2f(((const ushort_t*)al)[h2 * DK + d0 + n]);
            float bv = f32 ? ((const float*)ar)[h2 * DK + d0 + n]
                           : bf2f(((const ushort_t*)ar)[h2 * DK + d0 + n]);
            psl += wv * av;
            psr += wv * bv;
        }
        psl += __shfl_down(psl, 2); psl += __shfl_down(psl, 1);
        psr += __shfl_down(psr, 2); psr += __shfl_down(psr, 1);
        if (part == 0) {
            atomicAdd(&sl[h2 * N_NODES + i0 + m], psl);
            atomicAdd(&sr[h2 * N_NODES + i0 + m], psr);
        }
    }
}

// ---------------------------------------------------------------------------
// Kernel 3 v15: row-split waves + block-shared V windows.
// v14 diagnosis: latency-bound (all pipes <40%), 1024 blocks in 2 residency
// rounds, each wave privately DMA-ing its j-quarter => the 512KB (h,half)
// V-slice fetched 1024x (512MB L2 traffic).
// v15: block = 64 rows x one j-half; wave wq owns rows wq*16..+15; all 4
// waves share each 64j x 128d (16KB) V window staged ONCE per block via
// global_load_lds (4 calls/wave/window).  3-buffer rotation, counted
// vmcnt(4) (never 0 mid-loop), ONE raw s_barrier per window, DMA for w+2
// issued AFTER the barrier (all waves' w-1 reads completed) -- T3/T4.
// Row-split waves also kill the entire cross-wave reduction epilogue.
// Swizzles (both-sides-derived): V slot s of row d holds global j-chunk
// s^(d&7) (DMA source pre-swizzle); read slot (kk*4+quad)^(l15&7) -> 2-way
// bank access (free).  mbuf col c^r as proven in v12.
// Grid 512 = 64 i-tiles x 4 heads x 2 halves; 2 blocks/CU, single round.
// ---------------------------------------------------------------------------
__global__ __launch_bounds__(256, 2) void attn_split_k(const ushort_t* __restrict__ WhT,
                                                       const unsigned* __restrict__ Apack,
                                                       const float* __restrict__ sl,
                                                       const float* __restrict__ sr,
                                                       float* __restrict__ Npart,
                                                       float* __restrict__ Dpart)
{
    __shared__ char smem[73728] __attribute__((aligned(16)));
    float*    srs  = (float*)smem;                            // 2048 f32, 8 KB
    unsigned (*mbuf)[64] = (unsigned (*)[64])(smem + 8192);   // 64x64, 16 KB
    ushort_t* vbuf = (ushort_t*)(smem + 24576);               // 3 x 16 KB

    const int tid  = threadIdx.x;
    const int lane = tid & 63;
    const int wq   = tid >> 6;               // wave owns rows wq*16..+15
    const int quad = lane >> 4;
    const int l15  = lane & 15;
    const int bx   = blockIdx.x;
    const int half = bx & 1;
    const int h    = (bx >> 1) & 3;
    const int i0   = (bx >> 3) << 6;         // 64-row tile
    const int jbase = half << 11;            // 0 or 2048

    const float C1 = 1.44269504f;             // log2(e)

    for (int j = tid; j < 2048; j += 256) srs[j] = sr[h * N_NODES + jbase + j] * C1;
    for (int t = tid; t < 64 * 64; t += 256) {
        int r = t >> 6, c = t & 63;
        mbuf[r][c ^ r] = Apack[(size_t)(i0 + r) * 128 + (half << 6) + c];
    }
    const int myrow = wq * 16 + l15;
    const float slv = sl[h * N_NODES + i0 + myrow] * C1;
    __syncthreads();    // staging visible; drains all counters (no DMA yet)

    float4v acc[8];
    #pragma unroll
    for (int nt = 0; nt < 8; ++nt)
        #pragma unroll
        for (int e = 0; e < 4; ++e) acc[nt][e] = 0.f;
    float4v accden;
    #pragma unroll
    for (int e = 0; e < 4; ++e) accden[e] = 0.f;

    short8 ones;
    #pragma unroll
    for (int e = 0; e < 8; ++e) ones[e] = (short)0x3F80;   // bf16 1.0

    // DMA source: call q covers d = (wq*4+q)*8 + (lane>>3); LDS slot lane&7
    // holds global j-chunk p = (lane&7) ^ (d&7)  [pre-swizzled source].
    const int dl  = lane >> 3;
    const int pch = (lane & 7) ^ (dl & 7);
    const ushort_t* g0 = WhT + (size_t)(h * DK + wq * 32 + dl) * N_NODES + jbase + pch * 8;

    #define DMA_WIN(BUF, IW)                                                         \
        {   ushort_t* lb_ = vbuf + (BUF) * 8192 + wq * 2048;                         \
            const ushort_t* gs_ = g0 + (IW) * 64;                                    \
            _Pragma("unroll")                                                        \
            for (int q_ = 0; q_ < 4; ++q_)                                           \
                __builtin_amdgcn_global_load_lds(                                    \
                    (const __attribute__((address_space(1))) void*)(gs_ + (size_t)q_ * 8 * N_NODES), \
                    (__attribute__((address_space(3))) void*)(lb_ + q_ * 512),       \
                    16, 0, 0);                                                       \
        }

    DMA_WIN(0, 0)
    DMA_WIN(1, 1)

    const int rs0 = (quad     ^ (l15 & 7)) * 8;   // read slot, kk=0 (ushorts)
    const int rs1 = ((4 + quad) ^ (l15 & 7)) * 8; // read slot, kk=1

    #pragma unroll 1
    for (int iw = 0; iw < 32; ++iw) {
        const int jl = iw * 64;

        const unsigned wa0 = mbuf[myrow][(iw * 2)     ^ myrow];
        const unsigned wa1 = mbuf[myrow][(iw * 2 + 1) ^ myrow];
        const float4v s0 = *(const float4v*)&srs[jl + quad * 8];
        const float4v s1 = *(const float4v*)&srs[jl + quad * 8 + 4];
        const float4v s2 = *(const float4v*)&srs[jl + 32 + quad * 8];
        const float4v s3 = *(const float4v*)&srs[jl + 32 + quad * 8 + 4];

        short8 pfA, pfB;
        #pragma unroll
        for (int jj = 0; jj < 8; ++jj) {
            const int bit = quad * 8 + jj;
            float srjA = (jj < 4) ? s0[jj] : s1[jj - 4];
            float xA = slv + srjA;                       // both *C1
            float tA = fmaxf(xA, xA * 0.2f);
            tA = ((wa0 >> bit) & 1u) ? tA : -1e30f;
            pfA[jj] = (short)(ushort_t)(__float_as_uint(__builtin_amdgcn_exp2f(tA)) >> 16);
            float srjB = (jj < 4) ? s2[jj] : s3[jj - 4];
            float xB = slv + srjB;
            float tB = fmaxf(xB, xB * 0.2f);
            tB = ((wa1 >> bit) & 1u) ? tB : -1e30f;
            pfB[jj] = (short)(ushort_t)(__float_as_uint(__builtin_amdgcn_exp2f(tB)) >> 16);
        }

        if (iw == 31) { asm volatile("s_waitcnt vmcnt(0)" ::: "memory"); }
        else          { asm volatile("s_waitcnt vmcnt(4)" ::: "memory"); }
        asm volatile("s_barrier" ::: "memory");   // window iw landed for ALL waves;
                                                  // all waves' iw-1 reads are done
        if (iw < 30) DMA_WIN((iw + 2) % 3, iw + 2)

        const ushort_t* vB = vbuf + (iw % 3) * 8192;
        #pragma unroll
        for (int nt = 0; nt < 8; ++nt) {
            const int d64 = (nt * 16 + l15) * 64;
            short8 b0 = *(const short8*)(vB + d64 + rs0);
            short8 b1 = *(const short8*)(vB + d64 + rs1);
            acc[nt] = __builtin_amdgcn_mfma_f32_16x16x32_bf16(pfA, b0, acc[nt], 0, 0, 0);
            acc[nt] = __builtin_amdgcn_mfma_f32_16x16x32_bf16(pfB, b1, acc[nt], 0, 0, 0);
        }
        accden = __builtin_amdgcn_mfma_f32_16x16x32_bf16(pfA, ones, accden, 0, 0, 0);
        accden = __builtin_amdgcn_mfma_f32_16x16x32_bf16(pfB, ones, accden, 0, 0, 0);
    }
    #undef DMA_WIN

    // ---- epilogue: each wave owns its 16 rows — direct writes, no reduction ----
    float* Np = Npart + (size_t)half * N_NODES * ODIM;
    #pragma unroll
    for (int nt = 0; nt < 8; ++nt)
        #pragma unroll
        for (int r = 0; r < 4; ++r) {
            const int rowi = wq * 16 + quad * 4 + r;
            Np[(size_t)(i0 + rowi) * ODIM + h * DK + nt * 16 + l15] = acc[nt][r];
        }
    if (l15 == 0) {
        #pragma unroll
        for (int r = 0; r < 4; ++r) {
            const int rowi = wq * 16 + quad * 4 + r;
            Dpart[(half * 4 + h) * N_NODES + i0 + rowi] = accden[r];
        }
    }
}

// ---------------------------------------------------------------------------
// Kernel 4: merge halves, normalize, elu, store (dual-dtype out).
// ---------------------------------------------------------------------------
__global__ __launch_bounds__(256) void merge_k(const float* __restrict__ Npart,
                                               const float* __restrict__ Dpart,
                                               void* __restrict__ out,
                                               const int* __restrict__ flag)
{
    const int f32 = *flag;
    const size_t e4 = ((size_t)blockIdx.x * 256 + threadIdx.x) * 4;
    const int i = (int)(e4 >> 9);
    const int c = (int)(e4 & 511);
    const int h = c >> 7;
    const float4v n0 = *(const float4v*)(Npart + e4);
    const float4v n1 = *(const float4v*)(Npart + (size_t)N_NODES * ODIM + e4);
    const float den = Dpart[h * N_NODES + i] + Dpart[(4 + h) * N_NODES + i];
    const float rinv = 1.0f / fmaxf(den, 1e-37f);
    const float C1 = 1.44269504f;
    float o[4];
    #pragma unroll
    for (int k = 0; k < 4; ++k) {
        float v = (n0[k] + n1[k]) * rinv;
        float e = __builtin_amdgcn_exp2f(v * C1) - 1.0f;
        o[k] = (v > 0.f) ? v : e;
    }
    if (f32) {
        float4v ov;
        #pragma unroll
        for (int k = 0; k < 4; ++k) ov[k] = o[k];
        *(float4v*)((float*)out + e4) = ov;
    } else {
        short4v ov;
        #pragma unroll
        for (int k = 0; k < 4; ++k) ov[k] = (short)f2bf_rne(o[k]);
        *(short4v*)((ushort_t*)out + e4) = ov;
    }
}

// ---------------------------------------------------------------------------
// Fallback single-pass attention (R5 structure) if ws too small for partials.
// ---------------------------------------------------------------------------
__global__ __launch_bounds__(256, 2) void attn_single_k(const ushort_t* __restrict__ WhT,
                                                        const unsigned* __restrict__ Apack,
                                                        const float* __restrict__ sl,
                                                        const float* __restrict__ sr,
                                                        void* __restrict__ out,
                                                        const int* __restrict__ flag)
{
    __shared__ float    srs[N_NODES];
    __shared__ unsigned mbuf[32][128];
    __shared__ float    red[2][32][128];
    __shared__ float    lsum[4][32];

    const int f32  = *flag;
    const int tid  = threadIdx.x;
    const int lane = tid & 63;
    const int wq   = tid >> 6;
    const int quad = lane >> 4;
    const int l15  = lane & 15;
    const int h    = blockIdx.x & 3;
    const int i0   = (blockIdx.x >> 2) << 5;

    for (int j = tid; j < N_NODES; j += 256) srs[j] = sr[h * N_NODES + j];
    for (int t = tid; t < 32 * 128; t += 256) {
        int r = t >> 7, c = t & 127;
        mbuf[r][c] = Apack[(size_t)(i0 + r) * 128 + c];
    }
    const float slv0 = sl[h * N_NODES + i0 + l15];
    const float slv1 = sl[h * N_NODES + i0 + 16 + l15];
    __syncthreads();

    const float C1 = 1.44269504f;
    const float C2 = 0.2f * 1.44269504f;

    float4v acc[2][8];
    #pragma unroll
    for (int mg = 0; mg < 2; ++mg)
        #pragma unroll
        for (int nt = 0; nt < 8; ++nt)
            #pragma unroll
            for (int e = 0; e < 4; ++e) acc[mg][nt][e] = 0.f;
    float lacc0 = 0.f, lacc1 = 0.f;

    const ushort_t* vb = WhT + (size_t)(h * DK + l15) * N_NODES + wq * 1024 + quad * 8;

    #pragma unroll 1
    for (int it = 0; it < 16; ++it) {
        const int jl = it * 64;
        const int j0 = wq * 1024 + jl;
        const int mc = j0 >> 5;

        short8 bf[8][2];
        #pragma unroll
        for (int nt = 0; nt < 8; ++nt) {
            bf[nt][0] = *(const short8*)(vb + (size_t)nt * 16 * N_NODES + jl);
            bf[nt][1] = *(const short8*)(vb + (size_t)nt * 16 * N_NODES + jl + 32);
        }

        const unsigned wa0 = mbuf[l15][mc],      wa1 = mbuf[l15][mc + 1];
        const unsigned wb0 = mbuf[16 + l15][mc], wb1 = mbuf[16 + l15][mc + 1];

        short8 pf0[2], pf1[2];
        #pragma unroll
        for (int s = 0; s < 2; ++s) {
            const float* sp = &srs[j0 + s * 32 + quad * 8];
            const float4v s0 = *(const float4v*)sp;
            const float4v s1 = *(const float4v*)(sp + 4);
            const unsigned wa = s ? wa1 : wa0;
            const unsigned wb = s ? wb1 : wb0;
            #pragma unroll
            for (int jj = 0; jj < 8; ++jj) {
                float srj = (jj < 4) ? s0[jj] : s1[jj - 4];
                int bit = quad * 8 + jj;
                float x0 = slv0 + srj;
                float t0 = fmaxf(x0 * C1, x0 * C2);
                t0 = ((wa >> bit) & 1u) ? t0 : -1e30f;
                float p0 = __builtin_amdgcn_exp2f(t0);
                ushort_t h0 = (ushort_t)(__float_as_uint(p0) >> 16);
                lacc0 += bf2f(h0);
                pf0[s][jj] = (short)h0;
                float x1 = slv1 + srj;
                float t1 = fmaxf(x1 * C1, x1 * C2);
                t1 = ((wb >> bit) & 1u) ? t1 : -1e30f;
                float p1 = __builtin_amdgcn_exp2f(t1);
                ushort_t h1 = (ushort_t)(__float_as_uint(p1) >> 16);
                lacc1 += bf2f(h1);
                pf1[s][jj] = (short)h1;
            }
        }

        #pragma unroll
        for (int nt = 0; nt < 8; ++nt) {
            acc[0][nt] = __builtin_amdgcn_mfma_f32_16x16x32_bf16(pf0[0], bf[nt][0], acc[0][nt], 0, 0, 0);
            acc[0][nt] = __builtin_amdgcn_mfma_f32_16x16x32_bf16(pf0[1], bf[nt][1], acc[0][nt], 0, 0, 0);
            acc[1][nt] = __builtin_amdgcn_mfma_f32_16x16x32_bf16(pf1[0], bf[nt][0], acc[1][nt], 0, 0, 0);
            acc[1][nt] = __builtin_amdgcn_mfma_f32_16x16x32_bf16(pf1[1], bf[nt][1], acc[1][nt], 0, 0, 0);
        }
    }

    lacc0 += __shfl_xor(lacc0, 16);
    lacc0 += __shfl_xor(lacc0, 32);
    lacc1 += __shfl_xor(lacc1, 16);
    lacc1 += __shfl_xor(lacc1, 32);
    if (lane < 16) {
        lsum[wq][l15]      = lacc0;
        lsum[wq][16 + l15] = lacc1;
    }
    if (wq >= 2) {
        #pragma unroll
        for (int mg = 0; mg < 2; ++mg)
            #pragma unroll
            for (int nt = 0; nt < 8; ++nt)
                #pragma unroll
                for (int r = 0; r < 4; ++r)
                    red[wq - 2][mg * 16 + quad * 4 + r][nt * 16 + l15] = acc[mg][nt][r];
    }
    __syncthreads();
    if (wq < 2) {
        #pragma unroll
        for (int mg = 0; mg < 2; ++mg)
            #pragma unroll
            for (int nt = 0; nt < 8; ++nt)
                #pragma unroll
                for (int r = 0; r < 4; ++r)
                    acc[mg][nt][r] += red[wq][mg * 16 + quad * 4 + r][nt * 16 + l15];
    }
    __syncthreads();
    if (wq == 1) {
        #pragma unroll
        for (int mg = 0; mg < 2; ++mg)
            #pragma unroll
            for (int nt = 0; nt < 8; ++nt)
                #pragma unroll
                for (int r = 0; r < 4; ++r)
                    red[0][mg * 16 + quad * 4 + r][nt * 16 + l15] = acc[mg][nt][r];
    }
    __syncthreads();
    if (wq == 0) {
        #pragma unroll
        for (int mg = 0; mg < 2; ++mg) {
            float linv[4];
            #pragma unroll
            for (int r = 0; r < 4; ++r) {
                int rowi = mg * 16 + quad * 4 + r;
                float den = lsum[0][rowi] + lsum[1][rowi] + lsum[2][rowi] + lsum[3][rowi];
                linv[r] = 1.0f / fmaxf(den, 1e-37f);
            }
            #pragma unroll
            for (int nt = 0; nt < 8; ++nt)
                #pragma unroll
                for (int r = 0; r < 4; ++r) {
                    int rowi = mg * 16 + quad * 4 + r;
                    float v = (acc[mg][nt][r] + red[0][rowi][nt * 16 + l15]) * linv[r];
                    float e = __builtin_amdgcn_exp2f(v * C1) - 1.0f;
                    float o = (v > 0.f) ? v : e;
                    size_t oidx = (size_t)(i0 + rowi) * ODIM + h * DK + nt * 16 + l15;
                    if (f32) ((float*)out)[oidx] = o;
                    else     ((ushort_t*)out)[oidx] = f2bf_rne(o);
                }
        }
    }
}

// ---------------------------------------------------------------------------
extern "C" void kernel_launch(void* const* d_in, const int* in_sizes, int n_in,
                              void* d_out, int out_size, void* d_ws, size_t ws_size,
                              hipStream_t stream)
{
    const void* H  = d_in[0];
    const int*  A  = (const int*)d_in[1];
    const void* W  = d_in[2];
    const void* al = d_in[3];
    const void* ar = d_in[4];

    if (ws_size < (7u << 20)) return;

    char* ws = (char*)d_ws;
    ushort_t* WhT   = (ushort_t*)ws;                                    // 4 MB
    unsigned long long* Apack = (unsigned long long*)(ws + (4u << 20)); // 2 MB
    ushort_t* WT    = (ushort_t*)(ws + (6u << 20));                     // 512 KB
    float*    sl    = (float*)(ws + (6u << 20) + (512u << 10));         // 64 KB
    float*    sr    = (float*)(ws + (6u << 20) + (576u << 10));         // 64 KB
    int*      flag  = (int*)(ws + (6u << 20) + (640u << 10));           // 4 B
    float*    Npart = (float*)(ws + (12u << 20));                       // 16 MB
    float*    Dpart = (float*)(ws + (28u << 20));                       // 128 KB
    const bool have_split = ws_size >= (29u << 20);

    pack_mask_k    <<<16384, 256, 0, stream>>>(A, Apack, (const ushort_t*)H, flag,
                                               W, WT, sl, sr);
    gemm_wht_dual_k<<<512,   256, 0, stream>>>(H, WT, WhT, flag, al, ar, sl, sr);
    if (have_split) {
        attn_split_k<<<512, 256, 0, stream>>>(WhT, (const unsigned*)Apack, sl, sr, Npart, Dpart);
        merge_k     <<<2048, 256, 0, stream>>>(Npart, Dpart, (void*)d_out, flag);
    } else {
        attn_single_k<<<512, 256, 0, stream>>>(WhT, (const unsigned*)Apack, sl, sr, (void*)d_out, flag);
    }
}

// Round 6
// 169.714 us; speedup vs baseline: 1.5938x; 1.0251x over previous
//
#include <hip/hip_runtime.h>

typedef unsigned short ushort_t;
typedef __attribute__((ext_vector_type(8)))  short  short8;
typedef __attribute__((ext_vector_type(4)))  short  short4v;
typedef __attribute__((ext_vector_type(4)))  float  float4v;
typedef __attribute__((ext_vector_type(4)))  int    int4v;

#define N_NODES 4096
#define NHEADS  4
#define DK      128
#define ODIM    512
#define KDIM    512

__device__ __forceinline__ float bf2f(ushort_t u) {
    return __uint_as_float(((unsigned)u) << 16);
}
__device__ __forceinline__ ushort_t f2bf_rne(float f) {
    unsigned u = __float_as_uint(f);
    u += 0x7fffu + ((u >> 16) & 1u);
    return (ushort_t)(u >> 16);
}

// ---------------------------------------------------------------------------
// Kernel 1 (fused): mask bit-pack + dtype flag + W transpose + sl/sr zeroing.
// ---------------------------------------------------------------------------
__global__ __launch_bounds__(256) void pack_mask_k(const int* __restrict__ A,
                                                   unsigned long long* __restrict__ P,
                                                   const ushort_t* __restrict__ Hraw,
                                                   int* __restrict__ flag,
                                                   const void* __restrict__ W,
                                                   ushort_t* __restrict__ WT,
                                                   float* __restrict__ sl,
                                                   float* __restrict__ sr)
{
    __shared__ ushort_t lt[64][72];
    __shared__ int dcnt[4];
    const int tid = threadIdx.x;
    const int bx  = blockIdx.x;

    if (bx == 0 && tid < 64) {
        const int lane = tid;
        int cnt = 0;
        #pragma unroll
        for (int s = 0; s < 16; ++s) {
            ushort_t v = Hraw[(lane * 16 + s) * 2];
            int e = (v >> 7) & 0xFF;
            cnt += (((e >= 90) && (e <= 140)) || (v == 0)) ? 1 : 0;
        }
        #pragma unroll
        for (int off = 32; off; off >>= 1) cnt += __shfl_down(cnt, off);
        if (lane == 0) *flag = (cnt < 768) ? 1 : 0;
    }

    // ---- mask pack (all blocks) ----
    {
        const int lane  = tid & 63;
        const int flat4 = bx * 256 + tid;             // index in units of int4
        const int row   = flat4 >> 10;                // (flat4*4) >> 12
        const int col0  = (flat4 << 2) & 4095;
        const int4v a   = ((const int4v*)A)[flat4];
        unsigned nib = 0;
        #pragma unroll
        for (int j = 0; j < 4; ++j)
            nib |= ((a[j] != 0) || (row == col0 + j)) ? (1u << j) : 0u;
        unsigned long long v = (unsigned long long)nib << ((lane & 15) * 4);
        v |= __shfl_xor(v, 1);
        v |= __shfl_xor(v, 2);
        v |= __shfl_xor(v, 4);
        v |= __shfl_xor(v, 8);
        if ((lane & 15) == 0) P[flat4 >> 4] = v;
    }

    // ---- zero sl/sr (blocks 64..95): 8192 threads x one float4 ----
    if (bx >= 64 && bx < 96) {
        const int idx = (bx - 64) * 256 + tid;        // 0..8191
        float4v z;
        #pragma unroll
        for (int e = 0; e < 4; ++e) z[e] = 0.f;
        if (idx < 4096) ((float4v*)sl)[idx] = z;
        else            ((float4v*)sr)[idx - 4096] = z;
    }

    // ---- W transpose (blocks 0..63) ----
    if (bx < 64) {
        // block-local dtype detection (same 1024 samples as the global flag)
        int cnt = 0;
        #pragma unroll
        for (int s = 0; s < 4; ++s) {
            ushort_t v = Hraw[(tid * 4 + s) * 2];
            int e = (v >> 7) & 0xFF;
            cnt += (((e >= 90) && (e <= 140)) || (v == 0)) ? 1 : 0;
        }
        #pragma unroll
        for (int off = 32; off; off >>= 1) cnt += __shfl_down(cnt, off);
        if ((tid & 63) == 0) dcnt[tid >> 6] = cnt;
        __syncthreads();
        const int f32 = (dcnt[0] + dcnt[1] + dcnt[2] + dcnt[3]) < 768;

        const int ti = bx >> 3, tj = bx & 7;
        const int r = tid >> 2, c2 = tid & 3;
        const size_t eo = (size_t)(ti * 64 + r) * KDIM + tj * 64 + c2 * 16;
        if (f32) {
            const float4v* src = (const float4v*)((const float*)W + eo);
            float4v f0 = src[0], f1 = src[1], f2 = src[2], f3 = src[3];
            #pragma unroll
            for (int e = 0; e < 4; ++e) {
                lt[r][c2 * 16 +  0 + e] = f2bf_rne(f0[e]);
                lt[r][c2 * 16 +  4 + e] = f2bf_rne(f1[e]);
                lt[r][c2 * 16 +  8 + e] = f2bf_rne(f2[e]);
                lt[r][c2 * 16 + 12 + e] = f2bf_rne(f3[e]);
            }
        } else {
            const short8* src = (const short8*)((const ushort_t*)W + eo);
            short8 v0 = src[0];
            short8 v1 = src[1];
            *(short8*)&lt[r][c2 * 16]     = v0;
            *(short8*)&lt[r][c2 * 16 + 8] = v1;
        }
        __syncthreads();
        #pragma unroll
        for (int itr = 0; itr < 2; ++itr) {
            int idx = itr * 256 + tid;
            int n = idx >> 3, c = idx & 7;
            short8 vv;
            #pragma unroll
            for (int e = 0; e < 8; ++e) vv[e] = (short)lt[c * 8 + e][n];
            *(short8*)(WT + (size_t)(tj * 64 + n) * KDIM + ti * 64 + c * 8) = vv;
        }
    }
}

// ---------------------------------------------------------------------------
// Kernel 2 (fused): WhT[n][i] = (H @ W)[i][n] + sl/sr partial accumulation.
// ---------------------------------------------------------------------------
__global__ __launch_bounds__(256) void gemm_wht_dual_k(const void* __restrict__ H,
                                                       const ushort_t* __restrict__ WT,
                                                       ushort_t* __restrict__ WhT,
                                                       const int* __restrict__ flag,
                                                       const void* __restrict__ al,
                                                       const void* __restrict__ ar,
                                                       float* __restrict__ sl,
                                                       float* __restrict__ sr)
{
    __shared__ ushort_t lt[64][72];
    const int f32 = *flag;
    const int tid  = threadIdx.x;
    const int lane = tid & 63;
    const int wid  = tid >> 6;
    const int quad = lane >> 4;
    const int l15  = lane & 15;
    const int bm = blockIdx.x & 63, bn = blockIdx.x >> 6;
    const int i0 = bm * 64, n0 = bn * 64;

    const size_t aoff = (size_t)(i0 + wid * 16 + l15) * KDIM + quad * 8;
    const short8* bp0 = (const short8*)(WT + (size_t)(n0 +  0 + l15) * KDIM) + quad;
    const short8* bp1 = (const short8*)(WT + (size_t)(n0 + 16 + l15) * KDIM) + quad;
    const short8* bp2 = (const short8*)(WT + (size_t)(n0 + 32 + l15) * KDIM) + quad;
    const short8* bp3 = (const short8*)(WT + (size_t)(n0 + 48 + l15) * KDIM) + quad;

    float4v acc0, acc1, acc2, acc3;
    #pragma unroll
    for (int e = 0; e < 4; ++e) { acc0[e] = 0.f; acc1[e] = 0.f; acc2[e] = 0.f; acc3[e] = 0.f; }

    #pragma unroll 4
    for (int k8 = 0; k8 < 64; k8 += 4) {
        short8 a;
        if (f32) {
            const float4v* fp = (const float4v*)((const float*)H + aoff + (size_t)k8 * 8);
            float4v x0 = fp[0], x1 = fp[1];
            #pragma unroll
            for (int e = 0; e < 4; ++e) {
                a[e]     = (short)f2bf_rne(x0[e]);
                a[4 + e] = (short)f2bf_rne(x1[e]);
            }
        } else {
            a = *(const short8*)((const ushort_t*)H + aoff + (size_t)k8 * 8);
        }
        acc0 = __builtin_amdgcn_mfma_f32_16x16x32_bf16(a, bp0[k8], acc0, 0, 0, 0);
        acc1 = __builtin_amdgcn_mfma_f32_16x16x32_bf16(a, bp1[k8], acc1, 0, 0, 0);
        acc2 = __builtin_amdgcn_mfma_f32_16x16x32_bf16(a, bp2[k8], acc2, 0, 0, 0);
        acc3 = __builtin_amdgcn_mfma_f32_16x16x32_bf16(a, bp3[k8], acc3, 0, 0, 0);
    }

    #pragma unroll
    for (int r = 0; r < 4; ++r) {
        int m = wid * 16 + quad * 4 + r;
        lt[ 0 + l15][m] = f2bf_rne(acc0[r]);
        lt[16 + l15][m] = f2bf_rne(acc1[r]);
        lt[32 + l15][m] = f2bf_rne(acc2[r]);
        lt[48 + l15][m] = f2bf_rne(acc3[r]);
    }
    __syncthreads();
    #pragma unroll
    for (int itr = 0; itr < 2; ++itr) {
        int idx = itr * 256 + tid;
        int n = idx >> 3, c = idx & 7;
        short8 v = *(const short8*)&lt[n][c * 8];
        *(short8*)(WhT + (size_t)(n0 + n) * N_NODES + i0 + c * 8) = v;
    }

    // ---- fused slsr partials over this block's 64 d-values ----
    {
        const int h2 = n0 >> 7;          // head
        const int d0 = n0 & 127;         // d offset within head
        const int m  = tid >> 2;         // output row = i0 + m
        const int part = tid & 3;
        float psl = 0.f, psr = 0.f;
        #pragma unroll
        for (int k = 0; k < 16; ++k) {
            int n = part * 16 + k;
            float wv = bf2f(lt[n][m]);
            float av = f32 ? ((const float*)al)[h2 * DK + d0 + n]
                           : bf2f(((const ushort_t*)al)[h2 * DK + d0 + n]);
            float bv = f32 ? ((const float*)ar)[h2 * DK + d0 + n]
                           : bf2f(((const ushort_t*)ar)[h2 * DK + d0 + n]);
            psl += wv * av;
            psr += wv * bv;
        }
        psl += __shfl_down(psl, 2); psl += __shfl_down(psl, 1);
        psr += __shfl_down(psr, 2); psr += __shfl_down(psr, 1);
        if (part == 0) {
            atomicAdd(&sl[h2 * N_NODES + i0 + m], psl);
            atomicAdd(&sr[h2 * N_NODES + i0 + m], psr);
        }
    }
}

// ---------------------------------------------------------------------------
// Kernel 3 v16: 512-thread blocks = 8 waves = (row-group wq 0..3) x
// (j-substream js 0..1).  v15 diagnosis: VALU (pf compute) is the critical
// path at only 2 waves/SIMD (VALUBusy 40%, MfmaUtil 16%, memory fully
// hidden).  Same 72KB LDS but 512 threads -> 2 blocks/CU = 16 waves/CU =
// 4 waves/SIMD (2x TLP).  Each js-stream: 1024 j in 32 windows of 32j
// (8KB), private 3-buffer rotation (2x3x8KB=48KB), counted vmcnt(2),
// one raw s_barrier per window, DMA for iw+2 issued post-barrier (v15's
// proven pipeline).  js-pairs merge via one LDS reduction at the end.
// V swizzle (both-sides involution): slot s of d-row holds global chunk
// s ^ (d&3) ^ ((d>>2)&1); read slot = quad ^ (l15&3) ^ ((l15>>2)&1)
// -> <=2-way bank access (free).  mbuf col c^r as v12/v15.
// __launch_bounds__(512,4) caps VGPR at 128 (v15 used 88; spill signal =
// WRITE_SIZE jump, per v13 lesson).
// ---------------------------------------------------------------------------
__global__ __launch_bounds__(512, 4) void attn_split_k(const ushort_t* __restrict__ WhT,
                                                       const unsigned* __restrict__ Apack,
                                                       const float* __restrict__ sl,
                                                       const float* __restrict__ sr,
                                                       float* __restrict__ Npart,
                                                       float* __restrict__ Dpart)
{
    __shared__ char smem[73728] __attribute__((aligned(16)));
    float*    srs  = (float*)smem;                            // 2048 f32, 8 KB
    unsigned (*mbuf)[64] = (unsigned (*)[64])(smem + 8192);   // 64x64, 16 KB
    ushort_t* vbuf = (ushort_t*)(smem + 24576);               // 2 streams x 3 x 8 KB

    const int tid  = threadIdx.x;
    const int lane = tid & 63;
    const int wid  = tid >> 6;               // 0..7
    const int wq   = wid & 3;                // row group: rows wq*16..+15
    const int js   = wid >> 2;               // j substream 0/1
    const int quad = lane >> 4;
    const int l15  = lane & 15;
    const int bx   = blockIdx.x;
    const int half = bx & 1;
    const int h    = (bx >> 1) & 3;
    const int i0   = (bx >> 3) << 6;         // 64-row tile
    const int jbase = half << 11;            // 0 or 2048

    const float C1 = 1.44269504f;             // log2(e)

    for (int j = tid; j < 2048; j += 512) srs[j] = sr[h * N_NODES + jbase + j] * C1;
    for (int t = tid; t < 64 * 64; t += 512) {
        int r = t >> 6, c = t & 63;
        mbuf[r][c ^ r] = Apack[(size_t)(i0 + r) * 128 + (half << 6) + c];
    }
    const int myrow = wq * 16 + l15;
    const float slv = sl[h * N_NODES + i0 + myrow] * C1;
    __syncthreads();    // staging visible; drains all counters (no DMA yet)

    float4v acc[8];
    #pragma unroll
    for (int nt = 0; nt < 8; ++nt)
        #pragma unroll
        for (int e = 0; e < 4; ++e) acc[nt][e] = 0.f;
    float4v accden;
    #pragma unroll
    for (int e = 0; e < 4; ++e) accden[e] = 0.f;

    short8 ones;
    #pragma unroll
    for (int e = 0; e < 8; ++e) ones[e] = (short)0x3F80;   // bf16 1.0

    // DMA: window = 32j x 128d (8 KB).  Wave (wq,js) stages d-rows
    // [wq*32, +32) of its stream in 2 loads (q=0: rows +0..15, q=1: +16..31).
    // Lane L -> d-row base + (L>>2), LDS slot L&3; slot s of d-row holds
    // global chunk s ^ (d&3) ^ ((d>>2)&1)  [= s ^ (dl&3) ^ ((dl>>2)&1),
    // invariant under +16/+32 row offsets].
    const int dl  = lane >> 2;
    const int gch = (lane & 3) ^ (dl & 3) ^ ((dl >> 2) & 1);
    const ushort_t* g0 = WhT + (size_t)(h * DK + wq * 32 + dl) * N_NODES
                             + jbase + js * 1024 + gch * 8;

    #define DMA_WIN(BUF, IW)                                                         \
        {   ushort_t* lb_ = vbuf + js * 12288 + (BUF) * 4096 + wq * 1024;            \
            const ushort_t* gs_ = g0 + (IW) * 32;                                    \
            _Pragma("unroll")                                                        \
            for (int q_ = 0; q_ < 2; ++q_)                                           \
                __builtin_amdgcn_global_load_lds(                                    \
                    (const __attribute__((address_space(1))) void*)(gs_ + (size_t)q_ * 16 * N_NODES), \
                    (__attribute__((address_space(3))) void*)(lb_ + q_ * 512),       \
                    16, 0, 0);                                                       \
        }

    DMA_WIN(0, 0)
    DMA_WIN(1, 1)

    const int rs = (quad ^ (l15 & 3) ^ ((l15 >> 2) & 1)) * 8;   // read slot (ushorts)

    #pragma unroll 1
    for (int iw = 0; iw < 32; ++iw) {
        const unsigned wa = mbuf[myrow][(js * 32 + iw) ^ myrow];
        const float4v s0 = *(const float4v*)&srs[js * 1024 + iw * 32 + quad * 8];
        const float4v s1 = *(const float4v*)&srs[js * 1024 + iw * 32 + quad * 8 + 4];

        short8 pf;
        #pragma unroll
        for (int jj = 0; jj < 8; ++jj) {
            const int bit = quad * 8 + jj;
            float srj = (jj < 4) ? s0[jj] : s1[jj - 4];
            float x = slv + srj;                        // both *C1
            float t = fmaxf(x, x * 0.2f);
            t = ((wa >> bit) & 1u) ? t : -1e30f;
            pf[jj] = (short)(ushort_t)(__float_as_uint(__builtin_amdgcn_exp2f(t)) >> 16);
        }

        if (iw == 31) { asm volatile("s_waitcnt vmcnt(0)" ::: "memory"); }
        else          { asm volatile("s_waitcnt vmcnt(2)" ::: "memory"); }
        asm volatile("s_barrier" ::: "memory");   // window iw landed for ALL waves;
                                                  // all waves' iw-1 reads are done
        if (iw < 30) DMA_WIN((iw + 2) % 3, iw + 2)

        const ushort_t* vB = vbuf + js * 12288 + (iw % 3) * 4096;
        #pragma unroll
        for (int nt = 0; nt < 8; ++nt) {
            short8 b = *(const short8*)(vB + (nt * 16 + l15) * 32 + rs);
            acc[nt] = __builtin_amdgcn_mfma_f32_16x16x32_bf16(pf, b, acc[nt], 0, 0, 0);
        }
        accden = __builtin_amdgcn_mfma_f32_16x16x32_bf16(pf, ones, accden, 0, 0, 0);
    }
    #undef DMA_WIN

    // ---- epilogue: merge js=1 into js=0 (pairs share rows), then store ----
    float* red  = (float*)(smem + 24576);             // 4 wq x 16 x 128 f32 = 32 KB
    float* lsum = (float*)(smem + 24576 + 32768);     // 4 wq x 16 f32
    __syncthreads();                                   // all DMAs drained (vmcnt 0)

    if (js == 1) {
        #pragma unroll
        for (int nt = 0; nt < 8; ++nt)
            #pragma unroll
            for (int r = 0; r < 4; ++r)
                red[wq * 2048 + (quad * 4 + r) * 128 + nt * 16 + l15] = acc[nt][r];
        if (l15 == 0) {
            #pragma unroll
            for (int r = 0; r < 4; ++r)
                lsum[wq * 16 + quad * 4 + r] = accden[r];
        }
    }
    __syncthreads();
    if (js == 0) {
        float* Np = Npart + (size_t)half * N_NODES * ODIM;
        #pragma unroll
        for (int nt = 0; nt < 8; ++nt)
            #pragma unroll
            for (int r = 0; r < 4; ++r) {
                const int rowi = wq * 16 + quad * 4 + r;
                float v = acc[nt][r] + red[wq * 2048 + (quad * 4 + r) * 128 + nt * 16 + l15];
                Np[(size_t)(i0 + rowi) * ODIM + h * DK + nt * 16 + l15] = v;
            }
        if (l15 == 0) {
            #pragma unroll
            for (int r = 0; r < 4; ++r) {
                const int rowi = wq * 16 + quad * 4 + r;
                Dpart[(half * 4 + h) * N_NODES + i0 + rowi] =
                    accden[r] + lsum[wq * 16 + quad * 4 + r];
            }
        }
    }
}

// ---------------------------------------------------------------------------
// Kernel 4: merge halves, normalize, elu, store (dual-dtype out).
// ---------------------------------------------------------------------------
__global__ __launch_bounds__(256) void merge_k(const float* __restrict__ Npart,
                                               const float* __restrict__ Dpart,
                                               void* __restrict__ out,
                                               const int* __restrict__ flag)
{
    const int f32 = *flag;
    const size_t e4 = ((size_t)blockIdx.x * 256 + threadIdx.x) * 4;
    const int i = (int)(e4 >> 9);
    const int c = (int)(e4 & 511);
    const int h = c >> 7;
    const float4v n0 = *(const float4v*)(Npart + e4);
    const float4v n1 = *(const float4v*)(Npart + (size_t)N_NODES * ODIM + e4);
    const float den = Dpart[h * N_NODES + i] + Dpart[(4 + h) * N_NODES + i];
    const float rinv = 1.0f / fmaxf(den, 1e-37f);
    const float C1 = 1.44269504f;
    float o[4];
    #pragma unroll
    for (int k = 0; k < 4; ++k) {
        float v = (n0[k] + n1[k]) * rinv;
        float e = __builtin_amdgcn_exp2f(v * C1) - 1.0f;
        o[k] = (v > 0.f) ? v : e;
    }
    if (f32) {
        float4v ov;
        #pragma unroll
        for (int k = 0; k < 4; ++k) ov[k] = o[k];
        *(float4v*)((float*)out + e4) = ov;
    } else {
        short4v ov;
        #pragma unroll
        for (int k = 0; k < 4; ++k) ov[k] = (short)f2bf_rne(o[k]);
        *(short4v*)((ushort_t*)out + e4) = ov;
    }
}

// ---------------------------------------------------------------------------
// Fallback single-pass attention (R5 structure) if ws too small for partials.
// ---------------------------------------------------------------------------
__global__ __launch_bounds__(256, 2) void attn_single_k(const ushort_t* __restrict__ WhT,
                                                        const unsigned* __restrict__ Apack,
                                                        const float* __restrict__ sl,
                                                        const float* __restrict__ sr,
                                                        void* __restrict__ out,
                                                        const int* __restrict__ flag)
{
    __shared__ float    srs[N_NODES];
    __shared__ unsigned mbuf[32][128];
    __shared__ float    red[2][32][128];
    __shared__ float    lsum[4][32];

    const int f32  = *flag;
    const int tid  = threadIdx.x;
    const int lane = tid & 63;
    const int wq   = tid >> 6;
    const int quad = lane >> 4;
    const int l15  = lane & 15;
    const int h    = blockIdx.x & 3;
    const int i0   = (blockIdx.x >> 2) << 5;

    for (int j = tid; j < N_NODES; j += 256) srs[j] = sr[h * N_NODES + j];
    for (int t = tid; t < 32 * 128; t += 256) {
        int r = t >> 7, c = t & 127;
        mbuf[r][c] = Apack[(size_t)(i0 + r) * 128 + c];
    }
    const float slv0 = sl[h * N_NODES + i0 + l15];
    const float slv1 = sl[h * N_NODES + i0 + 16 + l15];
    __syncthreads();

    const float C1 = 1.44269504f;
    const float C2 = 0.2f * 1.44269504f;

    float4v acc[2][8];
    #pragma unroll
    for (int mg = 0; mg < 2; ++mg)
        #pragma unroll
        for (int nt = 0; nt < 8; ++nt)
            #pragma unroll
            for (int e = 0; e < 4; ++e) acc[mg][nt][e] = 0.f;
    float lacc0 = 0.f, lacc1 = 0.f;

    const ushort_t* vb = WhT + (size_t)(h * DK + l15) * N_NODES + wq * 1024 + quad * 8;

    #pragma unroll 1
    for (int it = 0; it < 16; ++it) {
        const int jl = it * 64;
        const int j0 = wq * 1024 + jl;
        const int mc = j0 >> 5;

        short8 bf[8][2];
        #pragma unroll
        for (int nt = 0; nt < 8; ++nt) {
            bf[nt][0] = *(const short8*)(vb + (size_t)nt * 16 * N_NODES + jl);
            bf[nt][1] = *(const short8*)(vb + (size_t)nt * 16 * N_NODES + jl + 32);
        }

        const unsigned wa0 = mbuf[l15][mc],      wa1 = mbuf[l15][mc + 1];
        const unsigned wb0 = mbuf[16 + l15][mc], wb1 = mbuf[16 + l15][mc + 1];

        short8 pf0[2], pf1[2];
        #pragma unroll
        for (int s = 0; s < 2; ++s) {
            const float* sp = &srs[j0 + s * 32 + quad * 8];
            const float4v s0 = *(const float4v*)sp;
            const float4v s1 = *(const float4v*)(sp + 4);
            const unsigned wa = s ? wa1 : wa0;
            const unsigned wb = s ? wb1 : wb0;
            #pragma unroll
            for (int jj = 0; jj < 8; ++jj) {
                float srj = (jj < 4) ? s0[jj] : s1[jj - 4];
                int bit = quad * 8 + jj;
                float x0 = slv0 + srj;
                float t0 = fmaxf(x0 * C1, x0 * C2);
                t0 = ((wa >> bit) & 1u) ? t0 : -1e30f;
                float p0 = __builtin_amdgcn_exp2f(t0);
                ushort_t h0 = (ushort_t)(__float_as_uint(p0) >> 16);
                lacc0 += bf2f(h0);
                pf0[s][jj] = (short)h0;
                float x1 = slv1 + srj;
                float t1 = fmaxf(x1 * C1, x1 * C2);
                t1 = ((wb >> bit) & 1u) ? t1 : -1e30f;
                float p1 = __builtin_amdgcn_exp2f(t1);
                ushort_t h1 = (ushort_t)(__float_as_uint(p1) >> 16);
                lacc1 += bf2f(h1);
                pf1[s][jj] = (short)h1;
            }
        }

        #pragma unroll
        for (int nt = 0; nt < 8; ++nt) {
            acc[0][nt] = __builtin_amdgcn_mfma_f32_16x16x32_bf16(pf0[0], bf[nt][0], acc[0][nt], 0, 0, 0);
            acc[0][nt] = __builtin_amdgcn_mfma_f32_16x16x32_bf16(pf0[1], bf[nt][1], acc[0][nt], 0, 0, 0);
            acc[1][nt] = __builtin_amdgcn_mfma_f32_16x16x32_bf16(pf1[0], bf[nt][0], acc[1][nt], 0, 0, 0);
            acc[1][nt] = __builtin_amdgcn_mfma_f32_16x16x32_bf16(pf1[1], bf[nt][1], acc[1][nt], 0, 0, 0);
        }
    }

    lacc0 += __shfl_xor(lacc0, 16);
    lacc0 += __shfl_xor(lacc0, 32);
    lacc1 += __shfl_xor(lacc1, 16);
    lacc1 += __shfl_xor(lacc1, 32);
    if (lane < 16) {
        lsum[wq][l15]      = lacc0;
        lsum[wq][16 + l15] = lacc1;
    }
    if (wq >= 2) {
        #pragma unroll
        for (int mg = 0; mg < 2; ++mg)
            #pragma unroll
            for (int nt = 0; nt < 8; ++nt)
                #pragma unroll
                for (int r = 0; r < 4; ++r)
                    red[wq - 2][mg * 16 + quad * 4 + r][nt * 16 + l15] = acc[mg][nt][r];
    }
    __syncthreads();
    if (wq < 2) {
        #pragma unroll
        for (int mg = 0; mg < 2; ++mg)
            #pragma unroll
            for (int nt = 0; nt < 8; ++nt)
                #pragma unroll
                for (int r = 0; r < 4; ++r)
                    acc[mg][nt][r] += red[wq][mg * 16 + quad * 4 + r][nt * 16 + l15];
    }
    __syncthreads();
    if (wq == 1) {
        #pragma unroll
        for (int mg = 0; mg < 2; ++mg)
            #pragma unroll
            for (int nt = 0; nt < 8; ++nt)
                #pragma unroll
                for (int r = 0; r < 4; ++r)
                    red[0][mg * 16 + quad * 4 + r][nt * 16 + l15] = acc[mg][nt][r];
    }
    __syncthreads();
    if (wq == 0) {
        #pragma unroll
        for (int mg = 0; mg < 2; ++mg) {
            float linv[4];
            #pragma unroll
            for (int r = 0; r < 4; ++r) {
                int rowi = mg * 16 + quad * 4 + r;
                float den = lsum[0][rowi] + lsum[1][rowi] + lsum[2][rowi] + lsum[3][rowi];
                linv[r] = 1.0f / fmaxf(den, 1e-37f);
            }
            #pragma unroll
            for (int nt = 0; nt < 8; ++nt)
                #pragma unroll
                for (int r = 0; r < 4; ++r) {
                    int rowi = mg * 16 + quad * 4 + r;
                    float v = (acc[mg][nt][r] + red[0][rowi][nt * 16 + l15]) * linv[r];
                    float e = __builtin_amdgcn_exp2f(v * C1) - 1.0f;
                    float o = (v > 0.f) ? v : e;
                    size_t oidx = (size_t)(i0 + rowi) * ODIM + h * DK + nt * 16 + l15;
                    if (f32) ((float*)out)[oidx] = o;
                    else     ((ushort_t*)out)[oidx] = f2bf_rne(o);
                }
        }
    }
}

// ---------------------------------------------------------------------------
extern "C" void kernel_launch(void* const* d_in, const int* in_sizes, int n_in,
                              void* d_out, int out_size, void* d_ws, size_t ws_size,
                              hipStream_t stream)
{
    const void* H  = d_in[0];
    const int*  A  = (const int*)d_in[1];
    const void* W  = d_in[2];
    const void* al = d_in[3];
    const void* ar = d_in[4];

    if (ws_size < (7u << 20)) return;

    char* ws = (char*)d_ws;
    ushort_t* WhT   = (ushort_t*)ws;                                    // 4 MB
    unsigned long long* Apack = (unsigned long long*)(ws + (4u << 20)); // 2 MB
    ushort_t* WT    = (ushort_t*)(ws + (6u << 20));                     // 512 KB
    float*    sl    = (float*)(ws + (6u << 20) + (512u << 10));         // 64 KB
    float*    sr    = (float*)(ws + (6u << 20) + (576u << 10));         // 64 KB
    int*      flag  = (int*)(ws + (6u << 20) + (640u << 10));           // 4 B
    float*    Npart = (float*)(ws + (12u << 20));                       // 16 MB
    float*    Dpart = (float*)(ws + (28u << 20));                       // 128 KB
    const bool have_split = ws_size >= (29u << 20);

    pack_mask_k    <<<16384, 256, 0, stream>>>(A, Apack, (const ushort_t*)H, flag,
                                               W, WT, sl, sr);
    gemm_wht_dual_k<<<512,   256, 0, stream>>>(H, WT, WhT, flag, al, ar, sl, sr);
    if (have_split) {
        attn_split_k<<<512, 512, 0, stream>>>(WhT, (const unsigned*)Apack, sl, sr, Npart, Dpart);
        merge_k     <<<2048, 256, 0, stream>>>(Npart, Dpart, (void*)d_out, flag);
    } else {
        attn_single_k<<<512, 256, 0, stream>>>(WhT, (const unsigned*)Apack, sl, sr, (void*)d_out, flag);
    }
}